// Round 5
// baseline (1875.852 us; speedup 1.0000x reference)
//
#include <hip/hip_runtime.h>

#define N_TOK 16384
#define ALPHA_LRELU 0.2f
#define NEGV -9e15f
#define NSPLIT 3
#define LOG2E 1.44269504f

typedef _Float16 f16;
typedef __attribute__((ext_vector_type(8))) _Float16 f16x8;
typedef __attribute__((ext_vector_type(4))) float f32x4;
typedef __attribute__((ext_vector_type(4))) int i32x4;
typedef unsigned short u16;
typedef unsigned long long u64;

__device__ __forceinline__ float bf2f(u16 b) {
  unsigned u = ((unsigned)b) << 16;
  return __builtin_bit_cast(float, u);
}
__device__ __forceinline__ f16x8 cvt8(i32x4 v) {
  f16x8 r;
#pragma unroll
  for (int i = 0; i < 4; ++i) {
    unsigned u = __builtin_bit_cast(unsigned, v[i]);
    r[2 * i]     = (f16)__builtin_bit_cast(float, (u & 0xffffu) << 16);
    r[2 * i + 1] = (f16)__builtin_bit_cast(float, u & 0xffff0000u);
  }
  return r;
}

// ---------------- kernel 0: input dtype detection (EVEN u16 parity) ----
__global__ __launch_bounds__(64) void detect_kernel(const u16* __restrict__ h16,
                                                    int* __restrict__ flag)
{
  int lane = threadIdx.x;
  unsigned u = h16[lane * 2];
  unsigned e = (u >> 7) & 0xFFu;
  int sane = (e >= 0x60u && e <= 0x8Eu) ? 1 : 0;
#pragma unroll
  for (int off = 32; off >= 1; off >>= 1) sane += __shfl_xor(sane, off);
  if (lane == 0) *flag = (sane >= 32) ? 1 : 0;  // 1 = bf16 inputs, 0 = fp32
}

// ---------------- kernel 0.5: ws-too-small sentinel ----------------
__global__ __launch_bounds__(256) void sentinel_kernel(float* __restrict__ out) {
  int i = blockIdx.x * 256 + threadIdx.x;
  if (i < N_TOK * 128) out[i] = 100.0f;
}

// ---------------- kernel 1: W transpose -> fp16 ----------------
// W_query additionally scaled by log2(e): scores arrive in log2 domain
// (leakyrelu commutes with positive scaling), so softmax uses exp2 directly.
__global__ __launch_bounds__(256) void wt_kernel(
    const int* __restrict__ flag,
    const void* __restrict__ Wq, const void* __restrict__ Wk,
    const void* __restrict__ Wv, f16* __restrict__ Wt)
{
  const int isbf = *flag;
  int w = blockIdx.y;
  const void* W = (w == 0) ? Wq : (w == 1) ? Wk : Wv;
  int idx = blockIdx.x * 256 + threadIdx.x;
  int k = idx >> 7, n = idx & 127;
  float v = isbf ? bf2f(((const u16*)W)[idx]) : ((const float*)W)[idx];
  if (w == 0) v *= LOG2E;
  Wt[w * 32768 + n * 256 + k] = (f16)v;
}

// ---------------- kernel 1.5: adjacency bit-pack ----------------
// adj [16384][16384] int32 (1 GiB) -> adjp [16384][256] u64 (32 MiB).
// bit kv of adjp[row][tile] = (adj[row][tile*64+kv] > 0).
// Payoff is NOT bandwidth (R4: flash unchanged with adj stream removed) —
// it is REGISTERS: dropping the pA prefetch (-16 VGPR) is what lets flash
// fit the (256,3) cap for 3 waves/SIMD. Costs ~175 us of streaming.
__global__ __launch_bounds__(256) void prepack_kernel(
    const int* __restrict__ adj, u64* __restrict__ adjp)
{
  const int lane = threadIdx.x & 63;
  const int gwave = blockIdx.x * 4 + (threadIdx.x >> 6);
  const int nwave = gridDim.x * 4;
  const int total_macro = N_TOK * 64;  // 16384 rows x 64 macros (4 tiles each)
  for (int m = gwave; m < total_macro; m += nwave) {
    int r  = m >> 6;
    int t4 = (m & 63) * 4;
    const int* base = adj + (size_t)r * N_TOK + t4 * 64 + lane;
    u64 b[4];
#pragma unroll
    for (int u = 0; u < 4; ++u) {
      int v = base[u * 64];
      b[u] = __ballot(v > 0);
    }
    if (lane == 0) {
      u64* dst = adjp + (size_t)r * 256 + t4;
      i32x4 w0, w1;
      w0[0] = (int)(unsigned)b[0]; w0[1] = (int)(b[0] >> 32);
      w0[2] = (int)(unsigned)b[1]; w0[3] = (int)(b[1] >> 32);
      w1[0] = (int)(unsigned)b[2]; w1[1] = (int)(b[2] >> 32);
      w1[2] = (int)(unsigned)b[3]; w1[3] = (int)(b[3] >> 32);
      *(i32x4*)dst       = w0;
      *(i32x4*)(dst + 2) = w1;
    }
  }
}

// ---------------- kernel 2: fused QKV GEMM ----------------
__global__ __launch_bounds__(256) void qkv_kernel(
    const int* __restrict__ flag, const void* __restrict__ hvp,
    const f16* __restrict__ Wt,
    f16* __restrict__ Qo, f16* __restrict__ Ko, f16* __restrict__ Vt)
{
  const int isbf = *flag;
  const int mb = blockIdx.x * 64;
  const int gy = blockIdx.y;
  const int tid = threadIdx.x;
  const int wave = tid >> 6, lane = tid & 63, quad = lane >> 4, l16 = lane & 15;

  __shared__ __align__(16) f16 hs[64][256 + 8];

  if (isbf) {
    const u16* h = (const u16*)hvp;
#pragma unroll
    for (int i = 0; i < 8; ++i) {
      int c = i * 256 + tid;
      int r = c >> 5, o = c & 31;
      i32x4 v = *(const i32x4*)(h + (size_t)(mb + r) * 256 + o * 8);
      *(f16x8*)(&hs[r][o * 8]) = cvt8(v);
    }
  } else {
    const float* h = (const float*)hvp;
#pragma unroll
    for (int i = 0; i < 8; ++i) {
      int c = i * 256 + tid;
      int r = c >> 5, o = c & 31;
      const float* p = h + (size_t)(mb + r) * 256 + o * 8;
      f32x4 v0 = *(const f32x4*)p, v1 = *(const f32x4*)(p + 4);
      f16x8 q;
#pragma unroll
      for (int j = 0; j < 4; ++j) { q[j] = (f16)v0[j]; q[4 + j] = (f16)v1[j]; }
      *(f16x8*)(&hs[r][o * 8]) = q;
    }
  }
  __syncthreads();

  const f16* Wg = Wt + gy * 32768;

  if (gy < 2) {
    f16x8 a[8];
#pragma unroll
    for (int ks = 0; ks < 8; ++ks)
      a[ks] = *(const f16x8*)(&hs[wave * 16 + l16][ks * 32 + quad * 8]);
    f32x4 acc[8];
#pragma unroll
    for (int ct = 0; ct < 8; ++ct) acc[ct] = (f32x4){0.f, 0.f, 0.f, 0.f};
#pragma unroll
    for (int ks = 0; ks < 8; ++ks)
#pragma unroll
      for (int ct = 0; ct < 8; ++ct) {
        f16x8 b = *(const f16x8*)(Wg + (ct * 16 + l16) * 256 + ks * 32 + quad * 8);
        acc[ct] = __builtin_amdgcn_mfma_f32_16x16x32_f16(a[ks], b, acc[ct], 0, 0, 0);
      }
    f16* O = (gy == 0) ? Qo : Ko;
#pragma unroll
    for (int ct = 0; ct < 8; ++ct)
#pragma unroll
      for (int r = 0; r < 4; ++r)
        O[(size_t)(mb + wave * 16 + quad * 4 + r) * 128 + ct * 16 + l16] = (f16)acc[ct][r];
  } else {
    f32x4 acc[2][4];
#pragma unroll
    for (int ft = 0; ft < 2; ++ft)
#pragma unroll
      for (int bt = 0; bt < 4; ++bt) acc[ft][bt] = (f32x4){0.f, 0.f, 0.f, 0.f};
#pragma unroll
    for (int ks = 0; ks < 8; ++ks) {
      f16x8 a2[2], b2[4];
#pragma unroll
      for (int ft = 0; ft < 2; ++ft)
        a2[ft] = *(const f16x8*)(Wg + ((wave * 2 + ft) * 16 + l16) * 256 + ks * 32 + quad * 8);
#pragma unroll
      for (int bt = 0; bt < 4; ++bt)
        b2[bt] = *(const f16x8*)(&hs[bt * 16 + l16][ks * 32 + quad * 8]);
#pragma unroll
      for (int ft = 0; ft < 2; ++ft)
#pragma unroll
        for (int bt = 0; bt < 4; ++bt)
          acc[ft][bt] = __builtin_amdgcn_mfma_f32_16x16x32_f16(a2[ft], b2[bt], acc[ft][bt], 0, 0, 0);
    }
#pragma unroll
    for (int ft = 0; ft < 2; ++ft)
#pragma unroll
      for (int bt = 0; bt < 4; ++bt)
#pragma unroll
        for (int r = 0; r < 4; ++r)
          Vt[(size_t)((wave * 2 + ft) * 16 + quad * 4 + r) * N_TOK + mb + bt * 16 + l16] =
              (f16)acc[ft][bt][r];
  }
}

// ---------------- kernel 3: flash attention, split-K x3, log2 domain ----
// adjacency from pre-packed bitmask (adjp), consumed straight from registers.
// REGISTER LAW (gfx950 unified VGPR/AGPR file; VGPR_Count reports arch half):
//   (256,3)@state~156 (R1, with pA) -> spilled prefetch, catastrophic.
//   no cap -> 264 total -> 1 wave/SIMD (R2). (256,2) -> 2 waves, 510us (R3/R4).
//   NOW: state ~140 (pA gone via adjp) under (256,3) cap=170 -> 3 waves/SIMD.
// Tripwires: WRITE_SIZE >> 25MB = spill; dur>=500us @ 85 VGPR = sunk prefetch.
__global__ __launch_bounds__(256, 3) void flash_kernel(
    const f16* __restrict__ Q, const f16* __restrict__ Kg,
    const f16* __restrict__ Vt, const u64* __restrict__ adjp,
    float* __restrict__ Opart, float* __restrict__ mpart,
    float* __restrict__ lpart)
{
  const int qb = blockIdx.x * 64;
  const int ksec = blockIdx.y;
  const int base = 256 / NSPLIT;                 // 85
  const int rem  = 256 % NSPLIT;                 // 1
  const int iters = base + (ksec < rem ? 1 : 0); // 86,85,85
  const int tile0 = ksec * base + (ksec < rem ? ksec : rem);
  const int kb0 = tile0 * 64;
  const int tid = threadIdx.x;
  const int wave = tid >> 6, lane = tid & 63, quad = lane >> 4, l16 = lane & 15;

  __shared__ __align__(16) f16 Ks[64][136];
  __shared__ __align__(16) f16 Vs[128][72];
  __shared__ __align__(16) f16 Ps[4][16][72];

  f16x8 qf[4];
#pragma unroll
  for (int ks = 0; ks < 4; ++ks)
    qf[ks] = *(const f16x8*)(Q + (size_t)(qb + wave * 16 + l16) * 128 + ks * 32 + quad * 8);

  f16x8 ONES;
#pragma unroll
  for (int j = 0; j < 8; ++j) ONES[j] = (f16)1.0f;

  // per-lane adjp row pointers (rows wave*16 + quad*4 + r), tile-indexed
  const u64* aprow = adjp + (size_t)(qb + wave * 16 + quad * 4) * 256 + tile0;

  f32x4 Oacc[8];
#pragma unroll
  for (int ot = 0; ot < 8; ++ot) Oacc[ot] = (f32x4){0.f, 0.f, 0.f, 0.f};
  f32x4 Lacc = (f32x4){0.f, 0.f, 0.f, 0.f};  // row-sum via MFMA-ones
  float m2[4];
#pragma unroll
  for (int r = 0; r < 4; ++r) m2[r] = -INFINITY;

  i32x4 pK[4], pV[4];
#pragma unroll
  for (int i = 0; i < 4; ++i) {
    int c = i * 256 + tid;
    pK[i] = *(const i32x4*)(Kg + (size_t)(kb0 + (c >> 4)) * 128 + (c & 15) * 8);
    pV[i] = *(const i32x4*)(Vt + (size_t)(c >> 3) * N_TOK + kb0 + (c & 7) * 8);
  }

  for (int it = 0; it < iters; ++it) {
    __syncthreads();
#pragma unroll
    for (int i = 0; i < 4; ++i) {
      int c = i * 256 + tid;
      *(f16x8*)(&Ks[c >> 4][(c & 15) * 8]) = __builtin_bit_cast(f16x8, pK[i]);
      *(f16x8*)(&Vs[c >> 3][(c & 7) * 8])  = __builtin_bit_cast(f16x8, pV[i]);
    }
    __syncthreads();
    // current-tile adjacency masks FIRST (so the later K/V prefetch stays
    // outstanding when the compiler waits for these before mask-apply)
    u64 au[4];
#pragma unroll
    for (int r = 0; r < 4; ++r) au[r] = aprow[(size_t)r * 256 + it];
    if (it + 1 < iters) {
      int kb = kb0 + (it + 1) * 64;
#pragma unroll
      for (int i = 0; i < 4; ++i) {
        int c = i * 256 + tid;
        pK[i] = *(const i32x4*)(Kg + (size_t)(kb + (c >> 4)) * 128 + (c & 15) * 8);
        pV[i] = *(const i32x4*)(Vt + (size_t)(c >> 3) * N_TOK + kb + (c & 7) * 8);
      }
    }

    // S(log2 domain) = Q K^T, leakyrelu
    float sc[4][4];
#pragma unroll
    for (int ct = 0; ct < 4; ++ct) {
      f32x4 s = (f32x4){0.f, 0.f, 0.f, 0.f};
#pragma unroll
      for (int ks = 0; ks < 4; ++ks) {
        f16x8 b = *(const f16x8*)(&Ks[ct * 16 + l16][ks * 32 + quad * 8]);
        s = __builtin_amdgcn_mfma_f32_16x16x32_f16(qf[ks], b, s, 0, 0, 0);
      }
#pragma unroll
      for (int r = 0; r < 4; ++r) {
        float v = s[r];
        sc[ct][r] = fmaxf(v, ALPHA_LRELU * v);
      }
    }
    // adjacency mask from packed bits: bit (ct*16+l16) of au[r]
#pragma unroll
    for (int r = 0; r < 4; ++r) {
      unsigned lo = (unsigned)au[r], hi = (unsigned)(au[r] >> 32);
      unsigned ta = lo >> l16, tb = hi >> l16;
      if (!(ta & 1u))       sc[0][r] = NEGV;
      if (!(ta & 0x10000u)) sc[1][r] = NEGV;
      if (!(tb & 1u))       sc[2][r] = NEGV;
      if (!(tb & 0x10000u)) sc[3][r] = NEGV;
    }

    // tile row max (16-lane butterfly within quad)
    float mx[4];
#pragma unroll
    for (int r = 0; r < 4; ++r) {
      float m = fmaxf(fmaxf(sc[0][r], sc[1][r]), fmaxf(sc[2][r], sc[3][r]));
#pragma unroll
      for (int off = 8; off >= 1; off >>= 1)
        m = fmaxf(m, __shfl_xor(m, off, 16));
      mx[r] = m;
    }
    // wave-uniform skip: rescale only if some row's max improved
    bool up = (mx[0] > m2[0]) | (mx[1] > m2[1]) | (mx[2] > m2[2]) | (mx[3] > m2[3]);
    if (__ballot(up)) {
      float al[4];
#pragma unroll
      for (int r = 0; r < 4; ++r) {
        float mn = fmaxf(m2[r], mx[r]);
        al[r] = exp2f(m2[r] - mn);
        m2[r] = mn;
      }
#pragma unroll
      for (int ot = 0; ot < 8; ++ot)
#pragma unroll
        for (int r = 0; r < 4; ++r) Oacc[ot][r] *= al[r];
#pragma unroll
      for (int r = 0; r < 4; ++r) Lacc[r] *= al[r];
    }

    // P = exp2(sc - m2), to LDS (C-layout -> A-layout round trip)
#pragma unroll
    for (int ct = 0; ct < 4; ++ct)
#pragma unroll
      for (int r = 0; r < 4; ++r)
        Ps[wave][quad * 4 + r][ct * 16 + l16] = (f16)exp2f(sc[ct][r] - m2[r]);

    asm volatile("s_waitcnt lgkmcnt(0)" ::: "memory");
    f16x8 pa0 = *(const f16x8*)(&Ps[wave][l16][quad * 8]);
    f16x8 pa1 = *(const f16x8*)(&Ps[wave][l16][32 + quad * 8]);
#pragma unroll
    for (int ot = 0; ot < 8; ++ot) {
      f16x8 b0 = *(const f16x8*)(&Vs[ot * 16 + l16][quad * 8]);
      f16x8 b1 = *(const f16x8*)(&Vs[ot * 16 + l16][32 + quad * 8]);
      Oacc[ot] = __builtin_amdgcn_mfma_f32_16x16x32_f16(pa0, b0, Oacc[ot], 0, 0, 0);
      Oacc[ot] = __builtin_amdgcn_mfma_f32_16x16x32_f16(pa1, b1, Oacc[ot], 0, 0, 0);
    }
    // row-sum of P via all-ones B (every lane gets the sum)
    Lacc = __builtin_amdgcn_mfma_f32_16x16x32_f16(pa0, ONES, Lacc, 0, 0, 0);
    Lacc = __builtin_amdgcn_mfma_f32_16x16x32_f16(pa1, ONES, Lacc, 0, 0, 0);
  }

  float* Op = Opart + (size_t)ksec * (N_TOK * 128);
#pragma unroll
  for (int ot = 0; ot < 8; ++ot)
#pragma unroll
    for (int r = 0; r < 4; ++r) {
      int row = qb + wave * 16 + quad * 4 + r;
      Op[(size_t)row * 128 + ot * 16 + l16] = Oacc[ot][r];
    }
  if (l16 == 0) {
#pragma unroll
    for (int r = 0; r < 4; ++r) {
      int row = qb + wave * 16 + quad * 4 + r;
      mpart[ksec * N_TOK + row] = m2[r];   // log2-domain max
      lpart[ksec * N_TOK + row] = Lacc[r];
    }
  }
}

// ---------------- kernel 4: split-K combine + elu (log2 domain) --------
__global__ __launch_bounds__(256) void combine_kernel(
    const float* __restrict__ Opart, const float* __restrict__ mpart,
    const float* __restrict__ lpart, float* __restrict__ out)
{
  const int qb = blockIdx.x * 64;
  const int t = threadIdx.x;
  __shared__ float sa[NSPLIT][64], sdn[64];
  if (t < 64) {
    float m = -INFINITY;
#pragma unroll
    for (int s = 0; s < NSPLIT; ++s) m = fmaxf(m, mpart[s * N_TOK + qb + t]);
    float dn = 0.f;
#pragma unroll
    for (int s = 0; s < NSPLIT; ++s) {
      float a = exp2f(mpart[s * N_TOK + qb + t] - m);
      sa[s][t] = a;
      dn += lpart[s * N_TOK + qb + t] * a;
    }
    sdn[t] = 1.0f / dn;
  }
  __syncthreads();
  float* Og = out + (size_t)qb * 128;
#pragma unroll
  for (int i = 0; i < 8; ++i) {
    int idx = (i * 256 + t) * 4;
    int row = idx >> 7;
    f32x4 acc = (f32x4){0.f, 0.f, 0.f, 0.f};
#pragma unroll
    for (int s = 0; s < NSPLIT; ++s) {
      f32x4 o = *(const f32x4*)(Opart + (size_t)s * (N_TOK * 128) + (size_t)qb * 128 + idx);
      float a = sa[s][row];
#pragma unroll
      for (int j = 0; j < 4; ++j) acc[j] += o[j] * a;
    }
    float dn = sdn[row];
    f32x4 v;
#pragma unroll
    for (int j = 0; j < 4; ++j) {
      float x = acc[j] * dn;
      v[j] = (x > 0.f) ? x : (__expf(x) - 1.f);
    }
    *(f32x4*)(Og + idx) = v;
  }
}

// ---------------- fallback: single-pass flash (ws too small) ----------
__global__ __launch_bounds__(256) void flash1_kernel(
    const f16* __restrict__ Q, const f16* __restrict__ Kg,
    const f16* __restrict__ Vt, const int* __restrict__ adj,
    float* __restrict__ out)
{
  const int qb = blockIdx.x * 64;
  const int tid = threadIdx.x;
  const int wave = tid >> 6, lane = tid & 63, quad = lane >> 4, l16 = lane & 15;

  __shared__ __align__(16) f16 Ks[64][136];
  __shared__ __align__(16) f16 Vs[128][72];
  __shared__ __align__(16) int As[64][68];
  __shared__ __align__(16) f16 Ps[4][16][72];

  f16x8 qf[4];
#pragma unroll
  for (int ks = 0; ks < 4; ++ks)
    qf[ks] = *(const f16x8*)(Q + (size_t)(qb + wave * 16 + l16) * 128 + ks * 32 + quad * 8);
  f16x8 ONES;
#pragma unroll
  for (int j = 0; j < 8; ++j) ONES[j] = (f16)1.0f;

  f32x4 Oacc[8];
#pragma unroll
  for (int ot = 0; ot < 8; ++ot) Oacc[ot] = (f32x4){0.f, 0.f, 0.f, 0.f};
  f32x4 Lacc = (f32x4){0.f, 0.f, 0.f, 0.f};
  float m2[4];
#pragma unroll
  for (int r = 0; r < 4; ++r) m2[r] = -INFINITY;

  i32x4 pK[4], pV[4], pA[4];
#pragma unroll
  for (int i = 0; i < 4; ++i) {
    int c = i * 256 + tid;
    pK[i] = *(const i32x4*)(Kg + (size_t)(c >> 4) * 128 + (c & 15) * 8);
    pV[i] = *(const i32x4*)(Vt + (size_t)(c >> 3) * N_TOK + (c & 7) * 8);
    pA[i] = *(const i32x4*)(adj + (size_t)(qb + (c >> 4)) * N_TOK + (c & 15) * 4);
  }

  for (int it = 0; it < 256; ++it) {
    __syncthreads();
#pragma unroll
    for (int i = 0; i < 4; ++i) {
      int c = i * 256 + tid;
      *(f16x8*)(&Ks[c >> 4][(c & 15) * 8]) = __builtin_bit_cast(f16x8, pK[i]);
      *(f16x8*)(&Vs[c >> 3][(c & 7) * 8])  = __builtin_bit_cast(f16x8, pV[i]);
      *(i32x4*)(&As[c >> 4][(c & 15) * 4]) = pA[i];
    }
    __syncthreads();
    if (it + 1 < 256) {
      int kb = (it + 1) * 64;
#pragma unroll
      for (int i = 0; i < 4; ++i) {
        int c = i * 256 + tid;
        pK[i] = *(const i32x4*)(Kg + (size_t)(kb + (c >> 4)) * 128 + (c & 15) * 8);
        pV[i] = *(const i32x4*)(Vt + (size_t)(c >> 3) * N_TOK + kb + (c & 7) * 8);
        pA[i] = *(const i32x4*)(adj + (size_t)(qb + (c >> 4)) * N_TOK + kb + (c & 15) * 4);
      }
    }
    float sc[4][4];
#pragma unroll
    for (int ct = 0; ct < 4; ++ct) {
      f32x4 s = (f32x4){0.f, 0.f, 0.f, 0.f};
#pragma unroll
      for (int ks = 0; ks < 4; ++ks) {
        f16x8 b = *(const f16x8*)(&Ks[ct * 16 + l16][ks * 32 + quad * 8]);
        s = __builtin_amdgcn_mfma_f32_16x16x32_f16(qf[ks], b, s, 0, 0, 0);
      }
#pragma unroll
      for (int r = 0; r < 4; ++r) {
        float v = s[r];
        v = fmaxf(v, ALPHA_LRELU * v);
        sc[ct][r] = (As[wave * 16 + quad * 4 + r][ct * 16 + l16] > 0) ? v : NEGV;
      }
    }
    float mx[4];
#pragma unroll
    for (int r = 0; r < 4; ++r) {
      float m = fmaxf(fmaxf(sc[0][r], sc[1][r]), fmaxf(sc[2][r], sc[3][r]));
#pragma unroll
      for (int off = 8; off >= 1; off >>= 1)
        m = fmaxf(m, __shfl_xor(m, off, 16));
      mx[r] = m;
    }
    bool up = (mx[0] > m2[0]) | (mx[1] > m2[1]) | (mx[2] > m2[2]) | (mx[3] > m2[3]);
    if (__ballot(up)) {
      float al[4];
#pragma unroll
      for (int r = 0; r < 4; ++r) {
        float mn = fmaxf(m2[r], mx[r]);
        al[r] = exp2f(m2[r] - mn);
        m2[r] = mn;
      }
#pragma unroll
      for (int ot = 0; ot < 8; ++ot)
#pragma unroll
        for (int r = 0; r < 4; ++r) Oacc[ot][r] *= al[r];
#pragma unroll
      for (int r = 0; r < 4; ++r) Lacc[r] *= al[r];
    }
#pragma unroll
    for (int ct = 0; ct < 4; ++ct)
#pragma unroll
      for (int r = 0; r < 4; ++r)
        Ps[wave][quad * 4 + r][ct * 16 + l16] = (f16)exp2f(sc[ct][r] - m2[r]);

    asm volatile("s_waitcnt lgkmcnt(0)" ::: "memory");
    f16x8 pa0 = *(const f16x8*)(&Ps[wave][l16][quad * 8]);
    f16x8 pa1 = *(const f16x8*)(&Ps[wave][l16][32 + quad * 8]);
#pragma unroll
    for (int ot = 0; ot < 8; ++ot) {
      f16x8 b0 = *(const f16x8*)(&Vs[ot * 16 + l16][quad * 8]);
      f16x8 b1 = *(const f16x8*)(&Vs[ot * 16 + l16][32 + quad * 8]);
      Oacc[ot] = __builtin_amdgcn_mfma_f32_16x16x32_f16(pa0, b0, Oacc[ot], 0, 0, 0);
      Oacc[ot] = __builtin_amdgcn_mfma_f32_16x16x32_f16(pa1, b1, Oacc[ot], 0, 0, 0);
    }
    Lacc = __builtin_amdgcn_mfma_f32_16x16x32_f16(pa0, ONES, Lacc, 0, 0, 0);
    Lacc = __builtin_amdgcn_mfma_f32_16x16x32_f16(pa1, ONES, Lacc, 0, 0, 0);
  }
#pragma unroll
  for (int ot = 0; ot < 8; ++ot)
#pragma unroll
    for (int r = 0; r < 4; ++r) {
      float v = Oacc[ot][r] / Lacc[r];
      v = (v > 0.f) ? v : (__expf(v) - 1.f);
      int row = qb + wave * 16 + quad * 4 + r;
      out[(size_t)row * 128 + ot * 16 + l16] = v;
    }
}

extern "C" void kernel_launch(void* const* d_in, const int* in_sizes, int n_in,
                              void* d_out, int out_size, void* d_ws, size_t ws_size,
                              hipStream_t stream)
{
  const void* h  = d_in[0];
  const int* adj = (const int*)d_in[1];
  const void* Wq = d_in[2];
  const void* Wk = d_in[3];
  const void* Wv = d_in[4];
  float* out = (float*)d_out;             // fp32 [16384][128]

  char* ws = (char*)d_ws;
  int* flag = (int*)ws;                    // @0
  f16* Wt = (f16*)(ws + 1024);             // 196608 B
  f16* Q  = (f16*)(ws + 262144);           // 4 MiB
  f16* K  = (f16*)(ws + 4456448);          // 4 MiB
  f16* Vt = (f16*)(ws + 8650752);          // 4 MiB -> 12845056
  u64* adjp = (u64*)(ws + 12845056);       // 32 MiB -> 46399488
  float* Opart = (float*)(ws + 46399488);  // 3 x 16384 x 128 f32 = 24 MiB
  float* mpart = (float*)(ws + 71565312);  // 3 x 16384 f32
  float* lpart = (float*)(ws + 71761920);  // 3 x 16384 f32 -> 71958528
  const size_t NEED_BASE  = 12845056;
  const size_t NEED_SPLIT = 71958528;

  if (ws_size < NEED_BASE) {
    sentinel_kernel<<<(N_TOK * 128 + 255) / 256, 256, 0, stream>>>(out);
    return;
  }

  detect_kernel<<<1, 64, 0, stream>>>((const u16*)h, flag);
  wt_kernel<<<dim3(128, 3), 256, 0, stream>>>(flag, Wq, Wk, Wv, Wt);
  qkv_kernel<<<dim3(256, 3), 256, 0, stream>>>(flag, h, Wt, Q, K, Vt);

  if (ws_size >= NEED_SPLIT) {
    // 1 GiB int32 adj -> 32 MiB bitmask at streaming BW
    prepack_kernel<<<2048, 256, 0, stream>>>(adj, adjp);
    // split-K x3: 768 blocks = exactly 3 resident/CU (LDS 44 KB, regs <=170)
    flash_kernel<<<dim3(256, NSPLIT), 256, 0, stream>>>(Q, K, Vt, adjp,
                                                        Opart, mpart, lpart);
    combine_kernel<<<dim3(256), 256, 0, stream>>>(Opart, mpart, lpart, out);
  } else {
    flash1_kernel<<<dim3(256), 256, 0, stream>>>(Q, K, Vt, adj, out);
  }
}

// Round 6
// 1597.703 us; speedup vs baseline: 1.1741x; 1.1741x over previous
//
#include <hip/hip_runtime.h>

#define N_TOK 16384
#define ALPHA_LRELU 0.2f
#define NEGV -9e15f
#define NSPLIT 3
#define LOG2E 1.44269504f
#define DEFER_THR 8.0f

typedef _Float16 f16;
typedef __attribute__((ext_vector_type(8))) _Float16 f16x8;
typedef __attribute__((ext_vector_type(4))) float f32x4;
typedef __attribute__((ext_vector_type(4))) int i32x4;
typedef unsigned short u16;

__device__ __forceinline__ float bf2f(u16 b) {
  unsigned u = ((unsigned)b) << 16;
  return __builtin_bit_cast(float, u);
}
__device__ __forceinline__ f16x8 cvt8(i32x4 v) {
  f16x8 r;
#pragma unroll
  for (int i = 0; i < 4; ++i) {
    unsigned u = __builtin_bit_cast(unsigned, v[i]);
    r[2 * i]     = (f16)__builtin_bit_cast(float, (u & 0xffffu) << 16);
    r[2 * i + 1] = (f16)__builtin_bit_cast(float, u & 0xffff0000u);
  }
  return r;
}

// ---------------- kernel 0: input dtype detection (EVEN u16 parity) ----
__global__ __launch_bounds__(64) void detect_kernel(const u16* __restrict__ h16,
                                                    int* __restrict__ flag)
{
  int lane = threadIdx.x;
  unsigned u = h16[lane * 2];
  unsigned e = (u >> 7) & 0xFFu;
  int sane = (e >= 0x60u && e <= 0x8Eu) ? 1 : 0;
#pragma unroll
  for (int off = 32; off >= 1; off >>= 1) sane += __shfl_xor(sane, off);
  if (lane == 0) *flag = (sane >= 32) ? 1 : 0;  // 1 = bf16 inputs, 0 = fp32
}

// ---------------- kernel 0.5: ws-too-small sentinel ----------------
__global__ __launch_bounds__(256) void sentinel_kernel(float* __restrict__ out) {
  int i = blockIdx.x * 256 + threadIdx.x;
  if (i < N_TOK * 128) out[i] = 100.0f;
}

// ---------------- kernel 1: W transpose -> fp16 ----------------
// W_query additionally scaled by log2(e): scores arrive in log2 domain
// (leakyrelu commutes with positive scaling), so softmax uses exp2 directly.
__global__ __launch_bounds__(256) void wt_kernel(
    const int* __restrict__ flag,
    const void* __restrict__ Wq, const void* __restrict__ Wk,
    const void* __restrict__ Wv, f16* __restrict__ Wt)
{
  const int isbf = *flag;
  int w = blockIdx.y;
  const void* W = (w == 0) ? Wq : (w == 1) ? Wk : Wv;
  int idx = blockIdx.x * 256 + threadIdx.x;
  int k = idx >> 7, n = idx & 127;
  float v = isbf ? bf2f(((const u16*)W)[idx]) : ((const float*)W)[idx];
  if (w == 0) v *= LOG2E;
  Wt[w * 32768 + n * 256 + k] = (f16)v;
}

// ---------------- kernel 2: fused QKV GEMM ----------------
__global__ __launch_bounds__(256) void qkv_kernel(
    const int* __restrict__ flag, const void* __restrict__ hvp,
    const f16* __restrict__ Wt,
    f16* __restrict__ Qo, f16* __restrict__ Ko, f16* __restrict__ Vt)
{
  const int isbf = *flag;
  const int mb = blockIdx.x * 64;
  const int gy = blockIdx.y;
  const int tid = threadIdx.x;
  const int wave = tid >> 6, lane = tid & 63, quad = lane >> 4, l16 = lane & 15;

  __shared__ __align__(16) f16 hs[64][256 + 8];

  if (isbf) {
    const u16* h = (const u16*)hvp;
#pragma unroll
    for (int i = 0; i < 8; ++i) {
      int c = i * 256 + tid;
      int r = c >> 5, o = c & 31;
      i32x4 v = *(const i32x4*)(h + (size_t)(mb + r) * 256 + o * 8);
      *(f16x8*)(&hs[r][o * 8]) = cvt8(v);
    }
  } else {
    const float* h = (const float*)hvp;
#pragma unroll
    for (int i = 0; i < 8; ++i) {
      int c = i * 256 + tid;
      int r = c >> 5, o = c & 31;
      const float* p = h + (size_t)(mb + r) * 256 + o * 8;
      f32x4 v0 = *(const f32x4*)p, v1 = *(const f32x4*)(p + 4);
      f16x8 q;
#pragma unroll
      for (int j = 0; j < 4; ++j) { q[j] = (f16)v0[j]; q[4 + j] = (f16)v1[j]; }
      *(f16x8*)(&hs[r][o * 8]) = q;
    }
  }
  __syncthreads();

  const f16* Wg = Wt + gy * 32768;

  if (gy < 2) {
    f16x8 a[8];
#pragma unroll
    for (int ks = 0; ks < 8; ++ks)
      a[ks] = *(const f16x8*)(&hs[wave * 16 + l16][ks * 32 + quad * 8]);
    f32x4 acc[8];
#pragma unroll
    for (int ct = 0; ct < 8; ++ct) acc[ct] = (f32x4){0.f, 0.f, 0.f, 0.f};
#pragma unroll
    for (int ks = 0; ks < 8; ++ks)
#pragma unroll
      for (int ct = 0; ct < 8; ++ct) {
        f16x8 b = *(const f16x8*)(Wg + (ct * 16 + l16) * 256 + ks * 32 + quad * 8);
        acc[ct] = __builtin_amdgcn_mfma_f32_16x16x32_f16(a[ks], b, acc[ct], 0, 0, 0);
      }
    f16* O = (gy == 0) ? Qo : Ko;
#pragma unroll
    for (int ct = 0; ct < 8; ++ct)
#pragma unroll
      for (int r = 0; r < 4; ++r)
        O[(size_t)(mb + wave * 16 + quad * 4 + r) * 128 + ct * 16 + l16] = (f16)acc[ct][r];
  } else {
    f32x4 acc[2][4];
#pragma unroll
    for (int ft = 0; ft < 2; ++ft)
#pragma unroll
      for (int bt = 0; bt < 4; ++bt) acc[ft][bt] = (f32x4){0.f, 0.f, 0.f, 0.f};
#pragma unroll
    for (int ks = 0; ks < 8; ++ks) {
      f16x8 a2[2], b2[4];
#pragma unroll
      for (int ft = 0; ft < 2; ++ft)
        a2[ft] = *(const f16x8*)(Wg + ((wave * 2 + ft) * 16 + l16) * 256 + ks * 32 + quad * 8);
#pragma unroll
      for (int bt = 0; bt < 4; ++bt)
        b2[bt] = *(const f16x8*)(&hs[bt * 16 + l16][ks * 32 + quad * 8]);
#pragma unroll
      for (int ft = 0; ft < 2; ++ft)
#pragma unroll
        for (int bt = 0; bt < 4; ++bt)
          acc[ft][bt] = __builtin_amdgcn_mfma_f32_16x16x32_f16(a2[ft], b2[bt], acc[ft][bt], 0, 0, 0);
    }
#pragma unroll
    for (int ft = 0; ft < 2; ++ft)
#pragma unroll
      for (int bt = 0; bt < 4; ++bt)
#pragma unroll
        for (int r = 0; r < 4; ++r)
          Vt[(size_t)((wave * 2 + ft) * 16 + quad * 4 + r) * N_TOK + mb + bt * 16 + l16] =
              (f16)acc[ft][bt][r];
  }
}

// ---------------- kernel 3: flash attention, split-K x3, log2 domain ----
// EXACTLY the R3 (1598us) structure: in-loop ballot-packed adjacency (512 B
// LDS), (256,2) launch bound, pK/pV/pA register prefetch — PLUS defer-max.
//
// REGISTER LAW (settled over R1/R2/R5): this loop needs ~2 waves/SIMD worth
// of registers. (256,3)/cap-170 fails twice (spill or sunk prefetch, flash
// 1191/613us). no-cap = 264 total = 1 wave/SIMD (696us). (256,2) = 510us.
//
// DEFER-MAX (T13, THR=8, log2 domain): skip the O/L rescale while tile max
// growth <= 8; P = exp2(sc - m2_old) <= 256 fits f16; accumulators are f32.
// Removes the rescale (36 mul + 4 exp2) from the serial chain between the
// max-butterfly and the P-compute for almost every iteration.
__global__ __launch_bounds__(256, 2) void flash_kernel(
    const f16* __restrict__ Q, const f16* __restrict__ Kg,
    const f16* __restrict__ Vt, const int* __restrict__ adj,
    float* __restrict__ Opart, float* __restrict__ mpart,
    float* __restrict__ lpart)
{
  const int qb = blockIdx.x * 64;
  const int ksec = blockIdx.y;
  const int base = 256 / NSPLIT;                 // 85
  const int rem  = 256 % NSPLIT;                 // 1
  const int iters = base + (ksec < rem ? 1 : 0); // 86,85,85
  const int tile0 = ksec * base + (ksec < rem ? ksec : rem);
  const int kb0 = tile0 * 64;
  const int tid = threadIdx.x;
  const int wave = tid >> 6, lane = tid & 63, quad = lane >> 4, l16 = lane & 15;

  __shared__ __align__(16) f16 Ks[64][136];
  __shared__ __align__(16) f16 Vs[128][72];
  __shared__ __align__(16) f16 Ps[4][16][72];
  __shared__ __align__(8)  u16 As16[64][4];

  f16x8 qf[4];
#pragma unroll
  for (int ks = 0; ks < 4; ++ks)
    qf[ks] = *(const f16x8*)(Q + (size_t)(qb + wave * 16 + l16) * 128 + ks * 32 + quad * 8);

  f16x8 ONES;
#pragma unroll
  for (int j = 0; j < 8; ++j) ONES[j] = (f16)1.0f;

  // mask-bit query shift: bit (l16&3)*16 + ct*4 + (l16>>2) of the packed row
  const int shq = (l16 & 3) * 16 + (l16 >> 2);

  f32x4 Oacc[8];
#pragma unroll
  for (int ot = 0; ot < 8; ++ot) Oacc[ot] = (f32x4){0.f, 0.f, 0.f, 0.f};
  f32x4 Lacc = (f32x4){0.f, 0.f, 0.f, 0.f};  // row-sum via MFMA-ones
  float m2[4];
#pragma unroll
  for (int r = 0; r < 4; ++r) m2[r] = -INFINITY;

  i32x4 pK[4], pV[4], pA[4];
#pragma unroll
  for (int i = 0; i < 4; ++i) {
    int c = i * 256 + tid;
    pK[i] = *(const i32x4*)(Kg + (size_t)(kb0 + (c >> 4)) * 128 + (c & 15) * 8);
    pV[i] = *(const i32x4*)(Vt + (size_t)(c >> 3) * N_TOK + kb0 + (c & 7) * 8);
    pA[i] = *(const i32x4*)(adj + (size_t)(qb + (c >> 4)) * N_TOK + kb0 + (c & 15) * 4);
  }

  for (int it = 0; it < iters; ++it) {
    __syncthreads();
#pragma unroll
    for (int i = 0; i < 4; ++i) {
      int c = i * 256 + tid;
      *(f16x8*)(&Ks[c >> 4][(c & 15) * 8]) = __builtin_bit_cast(f16x8, pK[i]);
      *(f16x8*)(&Vs[c >> 3][(c & 7) * 8])  = __builtin_bit_cast(f16x8, pV[i]);
      // ballot-pack adjacency: bit l of b_j = adj[row(i,wave,l>>4)][col (l&15)*4+j]
      unsigned long long b0 = __ballot(pA[i][0] > 0);
      unsigned long long b1 = __ballot(pA[i][1] > 0);
      unsigned long long b2 = __ballot(pA[i][2] > 0);
      unsigned long long b3 = __ballot(pA[i][3] > 0);
      if (lane < 16) {
        int j = lane & 3, g = lane >> 2;
        unsigned long long v = (j == 0) ? b0 : (j == 1) ? b1 : (j == 2) ? b2 : b3;
        As16[i * 16 + wave * 4 + g][j] = (u16)(v >> (16 * g));
      }
    }
    __syncthreads();
    if (it + 1 < iters) {
      int kb = kb0 + (it + 1) * 64;
#pragma unroll
      for (int i = 0; i < 4; ++i) {
        int c = i * 256 + tid;
        pK[i] = *(const i32x4*)(Kg + (size_t)(kb + (c >> 4)) * 128 + (c & 15) * 8);
        pV[i] = *(const i32x4*)(Vt + (size_t)(c >> 3) * N_TOK + kb + (c & 7) * 8);
        pA[i] = *(const i32x4*)(adj + (size_t)(qb + (c >> 4)) * N_TOK + kb + (c & 15) * 4);
      }
    }

    // S(log2 domain) = Q K^T, leakyrelu
    float sc[4][4];
#pragma unroll
    for (int ct = 0; ct < 4; ++ct) {
      f32x4 s = (f32x4){0.f, 0.f, 0.f, 0.f};
#pragma unroll
      for (int ks = 0; ks < 4; ++ks) {
        f16x8 b = *(const f16x8*)(&Ks[ct * 16 + l16][ks * 32 + quad * 8]);
        s = __builtin_amdgcn_mfma_f32_16x16x32_f16(qf[ks], b, s, 0, 0, 0);
      }
#pragma unroll
      for (int r = 0; r < 4; ++r) {
        float v = s[r];
        sc[ct][r] = fmaxf(v, ALPHA_LRELU * v);
      }
    }
    // adjacency mask from packed bits (broadcast b64 read per row)
#pragma unroll
    for (int r = 0; r < 4; ++r) {
      unsigned long long a64 =
          *(const unsigned long long*)(&As16[wave * 16 + quad * 4 + r][0]);
      unsigned y = (unsigned)(a64 >> shq);
#pragma unroll
      for (int ct = 0; ct < 4; ++ct)
        if (!((y >> (4 * ct)) & 1u)) sc[ct][r] = NEGV;
    }

    // tile row max (16-lane butterfly within quad)
    float mx[4];
#pragma unroll
    for (int r = 0; r < 4; ++r) {
      float m = fmaxf(fmaxf(sc[0][r], sc[1][r]), fmaxf(sc[2][r], sc[3][r]));
#pragma unroll
      for (int off = 8; off >= 1; off >>= 1)
        m = fmaxf(m, __shfl_xor(m, off, 16));
      mx[r] = m;
    }
    // DEFER-MAX: rescale only when some row's max grew by more than THR.
    // Otherwise keep m2; P = exp2(sc - m2) <= 2^THR = 256 (f16-safe).
    bool up = (mx[0] > m2[0] + DEFER_THR) | (mx[1] > m2[1] + DEFER_THR) |
              (mx[2] > m2[2] + DEFER_THR) | (mx[3] > m2[3] + DEFER_THR);
    if (__ballot(up)) {
      float al[4];
#pragma unroll
      for (int r = 0; r < 4; ++r) {
        float mn = fmaxf(m2[r], mx[r]);
        al[r] = exp2f(m2[r] - mn);
        m2[r] = mn;
      }
#pragma unroll
      for (int ot = 0; ot < 8; ++ot)
#pragma unroll
        for (int r = 0; r < 4; ++r) Oacc[ot][r] *= al[r];
#pragma unroll
      for (int r = 0; r < 4; ++r) Lacc[r] *= al[r];
    }

    // P = exp2(sc - m2), to LDS (C-layout -> A-layout round trip)
#pragma unroll
    for (int ct = 0; ct < 4; ++ct)
#pragma unroll
      for (int r = 0; r < 4; ++r)
        Ps[wave][quad * 4 + r][ct * 16 + l16] = (f16)exp2f(sc[ct][r] - m2[r]);

    asm volatile("s_waitcnt lgkmcnt(0)" ::: "memory");
    f16x8 pa0 = *(const f16x8*)(&Ps[wave][l16][quad * 8]);
    f16x8 pa1 = *(const f16x8*)(&Ps[wave][l16][32 + quad * 8]);
#pragma unroll
    for (int ot = 0; ot < 8; ++ot) {
      f16x8 b0 = *(const f16x8*)(&Vs[ot * 16 + l16][quad * 8]);
      f16x8 b1 = *(const f16x8*)(&Vs[ot * 16 + l16][32 + quad * 8]);
      Oacc[ot] = __builtin_amdgcn_mfma_f32_16x16x32_f16(pa0, b0, Oacc[ot], 0, 0, 0);
      Oacc[ot] = __builtin_amdgcn_mfma_f32_16x16x32_f16(pa1, b1, Oacc[ot], 0, 0, 0);
    }
    // row-sum of P via all-ones B (every lane gets the sum)
    Lacc = __builtin_amdgcn_mfma_f32_16x16x32_f16(pa0, ONES, Lacc, 0, 0, 0);
    Lacc = __builtin_amdgcn_mfma_f32_16x16x32_f16(pa1, ONES, Lacc, 0, 0, 0);
  }

  float* Op = Opart + (size_t)ksec * (N_TOK * 128);
#pragma unroll
  for (int ot = 0; ot < 8; ++ot)
#pragma unroll
    for (int r = 0; r < 4; ++r) {
      int row = qb + wave * 16 + quad * 4 + r;
      Op[(size_t)row * 128 + ot * 16 + l16] = Oacc[ot][r];
    }
  if (l16 == 0) {
#pragma unroll
    for (int r = 0; r < 4; ++r) {
      int row = qb + wave * 16 + quad * 4 + r;
      mpart[ksec * N_TOK + row] = m2[r];   // log2-domain (deferred) max
      lpart[ksec * N_TOK + row] = Lacc[r];
    }
  }
}

// ---------------- kernel 4: split-K combine + elu (log2 domain) --------
// Consistent O/m/l triples per split; deferred m2 is a valid reference max.
__global__ __launch_bounds__(256) void combine_kernel(
    const float* __restrict__ Opart, const float* __restrict__ mpart,
    const float* __restrict__ lpart, float* __restrict__ out)
{
  const int qb = blockIdx.x * 64;
  const int t = threadIdx.x;
  __shared__ float sa[NSPLIT][64], sdn[64];
  if (t < 64) {
    float m = -INFINITY;
#pragma unroll
    for (int s = 0; s < NSPLIT; ++s) m = fmaxf(m, mpart[s * N_TOK + qb + t]);
    float dn = 0.f;
#pragma unroll
    for (int s = 0; s < NSPLIT; ++s) {
      float a = exp2f(mpart[s * N_TOK + qb + t] - m);
      sa[s][t] = a;
      dn += lpart[s * N_TOK + qb + t] * a;
    }
    sdn[t] = 1.0f / dn;
  }
  __syncthreads();
  float* Og = out + (size_t)qb * 128;
#pragma unroll
  for (int i = 0; i < 8; ++i) {
    int idx = (i * 256 + t) * 4;
    int row = idx >> 7;
    f32x4 acc = (f32x4){0.f, 0.f, 0.f, 0.f};
#pragma unroll
    for (int s = 0; s < NSPLIT; ++s) {
      f32x4 o = *(const f32x4*)(Opart + (size_t)s * (N_TOK * 128) + (size_t)qb * 128 + idx);
      float a = sa[s][row];
#pragma unroll
      for (int j = 0; j < 4; ++j) acc[j] += o[j] * a;
    }
    float dn = sdn[row];
    f32x4 v;
#pragma unroll
    for (int j = 0; j < 4; ++j) {
      float x = acc[j] * dn;
      v[j] = (x > 0.f) ? x : (__expf(x) - 1.f);
    }
    *(f32x4*)(Og + idx) = v;
  }
}

// ---------------- fallback: single-pass flash (ws too small) ----------
__global__ __launch_bounds__(256) void flash1_kernel(
    const f16* __restrict__ Q, const f16* __restrict__ Kg,
    const f16* __restrict__ Vt, const int* __restrict__ adj,
    float* __restrict__ out)
{
  const int qb = blockIdx.x * 64;
  const int tid = threadIdx.x;
  const int wave = tid >> 6, lane = tid & 63, quad = lane >> 4, l16 = lane & 15;

  __shared__ __align__(16) f16 Ks[64][136];
  __shared__ __align__(16) f16 Vs[128][72];
  __shared__ __align__(16) int As[64][68];
  __shared__ __align__(16) f16 Ps[4][16][72];

  f16x8 qf[4];
#pragma unroll
  for (int ks = 0; ks < 4; ++ks)
    qf[ks] = *(const f16x8*)(Q + (size_t)(qb + wave * 16 + l16) * 128 + ks * 32 + quad * 8);
  f16x8 ONES;
#pragma unroll
  for (int j = 0; j < 8; ++j) ONES[j] = (f16)1.0f;

  f32x4 Oacc[8];
#pragma unroll
  for (int ot = 0; ot < 8; ++ot) Oacc[ot] = (f32x4){0.f, 0.f, 0.f, 0.f};
  f32x4 Lacc = (f32x4){0.f, 0.f, 0.f, 0.f};
  float m2[4];
#pragma unroll
  for (int r = 0; r < 4; ++r) m2[r] = -INFINITY;

  i32x4 pK[4], pV[4], pA[4];
#pragma unroll
  for (int i = 0; i < 4; ++i) {
    int c = i * 256 + tid;
    pK[i] = *(const i32x4*)(Kg + (size_t)(c >> 4) * 128 + (c & 15) * 8);
    pV[i] = *(const i32x4*)(Vt + (size_t)(c >> 3) * N_TOK + (c & 7) * 8);
    pA[i] = *(const i32x4*)(adj + (size_t)(qb + (c >> 4)) * N_TOK + (c & 15) * 4);
  }

  for (int it = 0; it < 256; ++it) {
    __syncthreads();
#pragma unroll
    for (int i = 0; i < 4; ++i) {
      int c = i * 256 + tid;
      *(f16x8*)(&Ks[c >> 4][(c & 15) * 8]) = __builtin_bit_cast(f16x8, pK[i]);
      *(f16x8*)(&Vs[c >> 3][(c & 7) * 8])  = __builtin_bit_cast(f16x8, pV[i]);
      *(i32x4*)(&As[c >> 4][(c & 15) * 4]) = pA[i];
    }
    __syncthreads();
    if (it + 1 < 256) {
      int kb = (it + 1) * 64;
#pragma unroll
      for (int i = 0; i < 4; ++i) {
        int c = i * 256 + tid;
        pK[i] = *(const i32x4*)(Kg + (size_t)(kb + (c >> 4)) * 128 + (c & 15) * 8);
        pV[i] = *(const i32x4*)(Vt + (size_t)(c >> 3) * N_TOK + kb + (c & 7) * 8);
        pA[i] = *(const i32x4*)(adj + (size_t)(qb + (c >> 4)) * N_TOK + kb + (c & 15) * 4);
      }
    }
    float sc[4][4];
#pragma unroll
    for (int ct = 0; ct < 4; ++ct) {
      f32x4 s = (f32x4){0.f, 0.f, 0.f, 0.f};
#pragma unroll
      for (int ks = 0; ks < 4; ++ks) {
        f16x8 b = *(const f16x8*)(&Ks[ct * 16 + l16][ks * 32 + quad * 8]);
        s = __builtin_amdgcn_mfma_f32_16x16x32_f16(qf[ks], b, s, 0, 0, 0);
      }
#pragma unroll
      for (int r = 0; r < 4; ++r) {
        float v = s[r];
        v = fmaxf(v, ALPHA_LRELU * v);
        sc[ct][r] = (As[wave * 16 + quad * 4 + r][ct * 16 + l16] > 0) ? v : NEGV;
      }
    }
    float mx[4];
#pragma unroll
    for (int r = 0; r < 4; ++r) {
      float m = fmaxf(fmaxf(sc[0][r], sc[1][r]), fmaxf(sc[2][r], sc[3][r]));
#pragma unroll
      for (int off = 8; off >= 1; off >>= 1)
        m = fmaxf(m, __shfl_xor(m, off, 16));
      mx[r] = m;
    }
    bool up = (mx[0] > m2[0] + DEFER_THR) | (mx[1] > m2[1] + DEFER_THR) |
              (mx[2] > m2[2] + DEFER_THR) | (mx[3] > m2[3] + DEFER_THR);
    if (__ballot(up)) {
      float al[4];
#pragma unroll
      for (int r = 0; r < 4; ++r) {
        float mn = fmaxf(m2[r], mx[r]);
        al[r] = exp2f(m2[r] - mn);
        m2[r] = mn;
      }
#pragma unroll
      for (int ot = 0; ot < 8; ++ot)
#pragma unroll
        for (int r = 0; r < 4; ++r) Oacc[ot][r] *= al[r];
#pragma unroll
      for (int r = 0; r < 4; ++r) Lacc[r] *= al[r];
    }
#pragma unroll
    for (int ct = 0; ct < 4; ++ct)
#pragma unroll
      for (int r = 0; r < 4; ++r)
        Ps[wave][quad * 4 + r][ct * 16 + l16] = (f16)exp2f(sc[ct][r] - m2[r]);

    asm volatile("s_waitcnt lgkmcnt(0)" ::: "memory");
    f16x8 pa0 = *(const f16x8*)(&Ps[wave][l16][quad * 8]);
    f16x8 pa1 = *(const f16x8*)(&Ps[wave][l16][32 + quad * 8]);
#pragma unroll
    for (int ot = 0; ot < 8; ++ot) {
      f16x8 b0 = *(const f16x8*)(&Vs[ot * 16 + l16][quad * 8]);
      f16x8 b1 = *(const f16x8*)(&Vs[ot * 16 + l16][32 + quad * 8]);
      Oacc[ot] = __builtin_amdgcn_mfma_f32_16x16x32_f16(pa0, b0, Oacc[ot], 0, 0, 0);
      Oacc[ot] = __builtin_amdgcn_mfma_f32_16x16x32_f16(pa1, b1, Oacc[ot], 0, 0, 0);
    }
    Lacc = __builtin_amdgcn_mfma_f32_16x16x32_f16(pa0, ONES, Lacc, 0, 0, 0);
    Lacc = __builtin_amdgcn_mfma_f32_16x16x32_f16(pa1, ONES, Lacc, 0, 0, 0);
  }
#pragma unroll
  for (int ot = 0; ot < 8; ++ot)
#pragma unroll
    for (int r = 0; r < 4; ++r) {
      float v = Oacc[ot][r] / Lacc[r];
      v = (v > 0.f) ? v : (__expf(v) - 1.f);
      int row = qb + wave * 16 + quad * 4 + r;
      out[(size_t)row * 128 + ot * 16 + l16] = v;
    }
}

extern "C" void kernel_launch(void* const* d_in, const int* in_sizes, int n_in,
                              void* d_out, int out_size, void* d_ws, size_t ws_size,
                              hipStream_t stream)
{
  const void* h  = d_in[0];
  const int* adj = (const int*)d_in[1];
  const void* Wq = d_in[2];
  const void* Wk = d_in[3];
  const void* Wv = d_in[4];
  float* out = (float*)d_out;             // fp32 [16384][128]

  char* ws = (char*)d_ws;
  int* flag = (int*)ws;                    // @0
  f16* Wt = (f16*)(ws + 1024);             // 196608 B
  f16* Q  = (f16*)(ws + 262144);           // 4 MiB
  f16* K  = (f16*)(ws + 4456448);          // 4 MiB
  f16* Vt = (f16*)(ws + 8650752);          // 4 MiB -> 12845056
  float* Opart = (float*)(ws + 12845056);  // 3 x 16384 x 128 f32 = 24 MiB
  float* mpart = (float*)(ws + 38010880);  // 3 x 16384 f32
  float* lpart = (float*)(ws + 38207488);  // 3 x 16384 f32 -> 38404096
  const size_t NEED_BASE  = 12845056;
  const size_t NEED_SPLIT = 38404096;

  if (ws_size < NEED_BASE) {
    sentinel_kernel<<<(N_TOK * 128 + 255) / 256, 256, 0, stream>>>(out);
    return;
  }

  detect_kernel<<<1, 64, 0, stream>>>((const u16*)h, flag);
  wt_kernel<<<dim3(128, 3), 256, 0, stream>>>(flag, Wq, Wk, Wv, Wt);
  qkv_kernel<<<dim3(256, 3), 256, 0, stream>>>(flag, h, Wt, Q, K, Vt);

  if (ws_size >= NEED_SPLIT) {
    // split-K x3: 768 blocks, 2 resident/CU (reg law), fine-grained backfill
    flash_kernel<<<dim3(256, NSPLIT), 256, 0, stream>>>(Q, K, Vt, adj,
                                                        Opart, mpart, lpart);
    combine_kernel<<<dim3(256), 256, 0, stream>>>(Opart, mpart, lpart, out);
  } else {
    flash1_kernel<<<dim3(256), 256, 0, stream>>>(Q, K, Vt, adj, out);
  }
}

// Round 7
// 1537.408 us; speedup vs baseline: 1.2201x; 1.0392x over previous
//
#include <hip/hip_runtime.h>

#define N_TOK 16384
#define ALPHA_LRELU 0.2f
#define NEGV -9e15f
#define NSPLIT 3
#define LOG2E 1.44269504f
#define DEFER_THR 8.0f

typedef _Float16 f16;
typedef __attribute__((ext_vector_type(8))) _Float16 f16x8;
typedef __attribute__((ext_vector_type(4))) float f32x4;
typedef __attribute__((ext_vector_type(4))) int i32x4;
typedef unsigned short u16;

__device__ __forceinline__ float bf2f(u16 b) {
  unsigned u = ((unsigned)b) << 16;
  return __builtin_bit_cast(float, u);
}
__device__ __forceinline__ f16x8 cvt8(i32x4 v) {
  f16x8 r;
#pragma unroll
  for (int i = 0; i < 4; ++i) {
    unsigned u = __builtin_bit_cast(unsigned, v[i]);
    r[2 * i]     = (f16)__builtin_bit_cast(float, (u & 0xffffu) << 16);
    r[2 * i + 1] = (f16)__builtin_bit_cast(float, u & 0xffff0000u);
  }
  return r;
}

// ---------------- kernel 0: input dtype detection (EVEN u16 parity) ----
__global__ __launch_bounds__(64) void detect_kernel(const u16* __restrict__ h16,
                                                    int* __restrict__ flag)
{
  int lane = threadIdx.x;
  unsigned u = h16[lane * 2];
  unsigned e = (u >> 7) & 0xFFu;
  int sane = (e >= 0x60u && e <= 0x8Eu) ? 1 : 0;
#pragma unroll
  for (int off = 32; off >= 1; off >>= 1) sane += __shfl_xor(sane, off);
  if (lane == 0) *flag = (sane >= 32) ? 1 : 0;  // 1 = bf16 inputs, 0 = fp32
}

// ---------------- kernel 0.5: ws-too-small sentinel ----------------
__global__ __launch_bounds__(256) void sentinel_kernel(float* __restrict__ out) {
  int i = blockIdx.x * 256 + threadIdx.x;
  if (i < N_TOK * 128) out[i] = 100.0f;
}

// ---------------- kernel 1: W transpose -> fp16 ----------------
// W_query additionally scaled by log2(e): scores arrive in log2 domain
// (leakyrelu commutes with positive scaling), so softmax uses exp2 directly.
__global__ __launch_bounds__(256) void wt_kernel(
    const int* __restrict__ flag,
    const void* __restrict__ Wq, const void* __restrict__ Wk,
    const void* __restrict__ Wv, f16* __restrict__ Wt)
{
  const int isbf = *flag;
  int w = blockIdx.y;
  const void* W = (w == 0) ? Wq : (w == 1) ? Wk : Wv;
  int idx = blockIdx.x * 256 + threadIdx.x;
  int k = idx >> 7, n = idx & 127;
  float v = isbf ? bf2f(((const u16*)W)[idx]) : ((const float*)W)[idx];
  if (w == 0) v *= LOG2E;
  Wt[w * 32768 + n * 256 + k] = (f16)v;
}

// ---------------- kernel 2: fused QKV GEMM ----------------
__global__ __launch_bounds__(256) void qkv_kernel(
    const int* __restrict__ flag, const void* __restrict__ hvp,
    const f16* __restrict__ Wt,
    f16* __restrict__ Qo, f16* __restrict__ Ko, f16* __restrict__ Vt)
{
  const int isbf = *flag;
  const int mb = blockIdx.x * 64;
  const int gy = blockIdx.y;
  const int tid = threadIdx.x;
  const int wave = tid >> 6, lane = tid & 63, quad = lane >> 4, l16 = lane & 15;

  __shared__ __align__(16) f16 hs[64][256 + 8];

  if (isbf) {
    const u16* h = (const u16*)hvp;
#pragma unroll
    for (int i = 0; i < 8; ++i) {
      int c = i * 256 + tid;
      int r = c >> 5, o = c & 31;
      i32x4 v = *(const i32x4*)(h + (size_t)(mb + r) * 256 + o * 8);
      *(f16x8*)(&hs[r][o * 8]) = cvt8(v);
    }
  } else {
    const float* h = (const float*)hvp;
#pragma unroll
    for (int i = 0; i < 8; ++i) {
      int c = i * 256 + tid;
      int r = c >> 5, o = c & 31;
      const float* p = h + (size_t)(mb + r) * 256 + o * 8;
      f32x4 v0 = *(const f32x4*)p, v1 = *(const f32x4*)(p + 4);
      f16x8 q;
#pragma unroll
      for (int j = 0; j < 4; ++j) { q[j] = (f16)v0[j]; q[4 + j] = (f16)v1[j]; }
      *(f16x8*)(&hs[r][o * 8]) = q;
    }
  }
  __syncthreads();

  const f16* Wg = Wt + gy * 32768;

  if (gy < 2) {
    f16x8 a[8];
#pragma unroll
    for (int ks = 0; ks < 8; ++ks)
      a[ks] = *(const f16x8*)(&hs[wave * 16 + l16][ks * 32 + quad * 8]);
    f32x4 acc[8];
#pragma unroll
    for (int ct = 0; ct < 8; ++ct) acc[ct] = (f32x4){0.f, 0.f, 0.f, 0.f};
#pragma unroll
    for (int ks = 0; ks < 8; ++ks)
#pragma unroll
      for (int ct = 0; ct < 8; ++ct) {
        f16x8 b = *(const f16x8*)(Wg + (ct * 16 + l16) * 256 + ks * 32 + quad * 8);
        acc[ct] = __builtin_amdgcn_mfma_f32_16x16x32_f16(a[ks], b, acc[ct], 0, 0, 0);
      }
    f16* O = (gy == 0) ? Qo : Ko;
#pragma unroll
    for (int ct = 0; ct < 8; ++ct)
#pragma unroll
      for (int r = 0; r < 4; ++r)
        O[(size_t)(mb + wave * 16 + quad * 4 + r) * 128 + ct * 16 + l16] = (f16)acc[ct][r];
  } else {
    f32x4 acc[2][4];
#pragma unroll
    for (int ft = 0; ft < 2; ++ft)
#pragma unroll
      for (int bt = 0; bt < 4; ++bt) acc[ft][bt] = (f32x4){0.f, 0.f, 0.f, 0.f};
#pragma unroll
    for (int ks = 0; ks < 8; ++ks) {
      f16x8 a2[2], b2[4];
#pragma unroll
      for (int ft = 0; ft < 2; ++ft)
        a2[ft] = *(const f16x8*)(Wg + ((wave * 2 + ft) * 16 + l16) * 256 + ks * 32 + quad * 8);
#pragma unroll
      for (int bt = 0; bt < 4; ++bt)
        b2[bt] = *(const f16x8*)(&hs[bt * 16 + l16][ks * 32 + quad * 8]);
#pragma unroll
      for (int ft = 0; ft < 2; ++ft)
#pragma unroll
        for (int bt = 0; bt < 4; ++bt)
          acc[ft][bt] = __builtin_amdgcn_mfma_f32_16x16x32_f16(a2[ft], b2[bt], acc[ft][bt], 0, 0, 0);
    }
#pragma unroll
    for (int ft = 0; ft < 2; ++ft)
#pragma unroll
      for (int bt = 0; bt < 4; ++bt)
#pragma unroll
        for (int r = 0; r < 4; ++r)
          Vt[(size_t)((wave * 2 + ft) * 16 + quad * 4 + r) * N_TOK + mb + bt * 16 + l16] =
              (f16)acc[ft][bt][r];
  }
}

// ---------------- kernel 3: flash attention, split-K x3, log2 domain ----
// ROUND-7 STRUCTURE: double-buffered K/V LDS, ONE barrier per iteration
// (write next tile -> buf^1 overlaps compute from buf), and adjacency
// masks loaded DIRECTLY into per-lane registers (am[r][ct]) — no ballot,
// no As16 LDS, no bit unpacking. Same HBM bytes (R4 proved adj is free).
//
// REGISTER LAW (settled R1/R2/R5): ~2 waves/SIMD of regs needed. (256,2)
// cap=256 total regs -> no spill. (256,3) fails (spill/sunk prefetch).
// LDS = 2*17408(K) + 2*18432(V) + 9216(Ps) = 80896 B -> 2 blocks/CU.
// Tripwires: Occupancy ~12% -> LDS didn't fit 2 blocks; WRITE>>25MB -> spill.
__global__ __launch_bounds__(256, 2) void flash_kernel(
    const f16* __restrict__ Q, const f16* __restrict__ Kg,
    const f16* __restrict__ Vt, const int* __restrict__ adj,
    float* __restrict__ Opart, float* __restrict__ mpart,
    float* __restrict__ lpart)
{
  const int qb = blockIdx.x * 64;
  const int ksec = blockIdx.y;
  const int base = 256 / NSPLIT;                 // 85
  const int rem  = 256 % NSPLIT;                 // 1
  const int iters = base + (ksec < rem ? 1 : 0); // 86,85,85
  const int tile0 = ksec * base + (ksec < rem ? ksec : rem);
  const int kb0 = tile0 * 64;
  const int tid = threadIdx.x;
  const int wave = tid >> 6, lane = tid & 63, quad = lane >> 4, l16 = lane & 15;

  __shared__ __align__(16) f16 Ks[2][64][136];
  __shared__ __align__(16) f16 Vs[2][128][72];
  __shared__ __align__(16) f16 Ps[4][16][72];

  f16x8 qf[4];
#pragma unroll
  for (int ks = 0; ks < 4; ++ks)
    qf[ks] = *(const f16x8*)(Q + (size_t)(qb + wave * 16 + l16) * 128 + ks * 32 + quad * 8);

  f16x8 ONES;
#pragma unroll
  for (int j = 0; j < 8; ++j) ONES[j] = (f16)1.0f;

  // per-lane adjacency row pointers: lane (quad,l16) owns rows quad*4+r,
  // col slots ct*16+l16 — exactly the sc[ct][r] cells it computes.
  const int* aprow[4];
#pragma unroll
  for (int r = 0; r < 4; ++r)
    aprow[r] = adj + (size_t)(qb + wave * 16 + quad * 4 + r) * N_TOK + l16;

  f32x4 Oacc[8];
#pragma unroll
  for (int ot = 0; ot < 8; ++ot) Oacc[ot] = (f32x4){0.f, 0.f, 0.f, 0.f};
  f32x4 Lacc = (f32x4){0.f, 0.f, 0.f, 0.f};  // row-sum via MFMA-ones
  float m2[4];
#pragma unroll
  for (int r = 0; r < 4; ++r) m2[r] = -INFINITY;

  i32x4 pK[4], pV[4];
  int am[4][4];  // current tile's masks, prefetched 1 tile ahead

  // -------- prologue: tile0 -> buf0, then prefetch tile1 --------
#pragma unroll
  for (int i = 0; i < 4; ++i) {
    int c = i * 256 + tid;
    pK[i] = *(const i32x4*)(Kg + (size_t)(kb0 + (c >> 4)) * 128 + (c & 15) * 8);
    pV[i] = *(const i32x4*)(Vt + (size_t)(c >> 3) * N_TOK + kb0 + (c & 7) * 8);
  }
#pragma unroll
  for (int r = 0; r < 4; ++r)
#pragma unroll
    for (int ct = 0; ct < 4; ++ct)
      am[r][ct] = aprow[r][kb0 + ct * 16];
#pragma unroll
  for (int i = 0; i < 4; ++i) {
    int c = i * 256 + tid;
    *(f16x8*)(&Ks[0][c >> 4][(c & 15) * 8]) = __builtin_bit_cast(f16x8, pK[i]);
    *(f16x8*)(&Vs[0][c >> 3][(c & 7) * 8])  = __builtin_bit_cast(f16x8, pV[i]);
  }
  if (iters > 1) {
    int kb = kb0 + 64;
#pragma unroll
    for (int i = 0; i < 4; ++i) {
      int c = i * 256 + tid;
      pK[i] = *(const i32x4*)(Kg + (size_t)(kb + (c >> 4)) * 128 + (c & 15) * 8);
      pV[i] = *(const i32x4*)(Vt + (size_t)(c >> 3) * N_TOK + kb + (c & 7) * 8);
    }
  }
  __syncthreads();

  for (int it = 0; it < iters; ++it) {
    const int cur = it & 1;
    const int nxt = cur ^ 1;

    // 1. write tile it+1 into the other buffer (overlaps compute of buf cur)
    if (it + 1 < iters) {
#pragma unroll
      for (int i = 0; i < 4; ++i) {
        int c = i * 256 + tid;
        *(f16x8*)(&Ks[nxt][c >> 4][(c & 15) * 8]) = __builtin_bit_cast(f16x8, pK[i]);
        *(f16x8*)(&Vs[nxt][c >> 3][(c & 7) * 8])  = __builtin_bit_cast(f16x8, pV[i]);
      }
    }
    // 2. issue K/V loads for tile it+2
    if (it + 2 < iters) {
      int kb = kb0 + (it + 2) * 64;
#pragma unroll
      for (int i = 0; i < 4; ++i) {
        int c = i * 256 + tid;
        pK[i] = *(const i32x4*)(Kg + (size_t)(kb + (c >> 4)) * 128 + (c & 15) * 8);
        pV[i] = *(const i32x4*)(Vt + (size_t)(c >> 3) * N_TOK + kb + (c & 7) * 8);
      }
    }

    // 3. S(log2 domain) = Q K^T from Ks[cur]; leakyrelu; mask from registers
    float sc[4][4];
#pragma unroll
    for (int ct = 0; ct < 4; ++ct) {
      f32x4 s = (f32x4){0.f, 0.f, 0.f, 0.f};
#pragma unroll
      for (int ks = 0; ks < 4; ++ks) {
        f16x8 b = *(const f16x8*)(&Ks[cur][ct * 16 + l16][ks * 32 + quad * 8]);
        s = __builtin_amdgcn_mfma_f32_16x16x32_f16(qf[ks], b, s, 0, 0, 0);
      }
#pragma unroll
      for (int r = 0; r < 4; ++r) {
        float v = s[r];
        v = fmaxf(v, ALPHA_LRELU * v);
        sc[ct][r] = (am[r][ct] > 0) ? v : NEGV;
      }
    }
    // 4. prefetch next tile's masks (AFTER use — WAR pins the order)
    if (it + 1 < iters) {
      int kb = kb0 + (it + 1) * 64;
#pragma unroll
      for (int r = 0; r < 4; ++r)
#pragma unroll
        for (int ct = 0; ct < 4; ++ct)
          am[r][ct] = aprow[r][kb + ct * 16];
    }

    // 5. tile row max (16-lane butterfly within quad)
    float mx[4];
#pragma unroll
    for (int r = 0; r < 4; ++r) {
      float m = fmaxf(fmaxf(sc[0][r], sc[1][r]), fmaxf(sc[2][r], sc[3][r]));
#pragma unroll
      for (int off = 8; off >= 1; off >>= 1)
        m = fmaxf(m, __shfl_xor(m, off, 16));
      mx[r] = m;
    }
    // defer-max: rescale only when some row's max grew by more than THR
    bool up = (mx[0] > m2[0] + DEFER_THR) | (mx[1] > m2[1] + DEFER_THR) |
              (mx[2] > m2[2] + DEFER_THR) | (mx[3] > m2[3] + DEFER_THR);
    if (__ballot(up)) {
      float al[4];
#pragma unroll
      for (int r = 0; r < 4; ++r) {
        float mn = fmaxf(m2[r], mx[r]);
        al[r] = exp2f(m2[r] - mn);
        m2[r] = mn;
      }
#pragma unroll
      for (int ot = 0; ot < 8; ++ot)
#pragma unroll
        for (int r = 0; r < 4; ++r) Oacc[ot][r] *= al[r];
#pragma unroll
      for (int r = 0; r < 4; ++r) Lacc[r] *= al[r];
    }

    // 6. P = exp2(sc - m2), LDS round trip (C-layout -> A-layout), PV
#pragma unroll
    for (int ct = 0; ct < 4; ++ct)
#pragma unroll
      for (int r = 0; r < 4; ++r)
        Ps[wave][quad * 4 + r][ct * 16 + l16] = (f16)exp2f(sc[ct][r] - m2[r]);

    asm volatile("s_waitcnt lgkmcnt(0)" ::: "memory");
    f16x8 pa0 = *(const f16x8*)(&Ps[wave][l16][quad * 8]);
    f16x8 pa1 = *(const f16x8*)(&Ps[wave][l16][32 + quad * 8]);
#pragma unroll
    for (int ot = 0; ot < 8; ++ot) {
      f16x8 b0 = *(const f16x8*)(&Vs[cur][ot * 16 + l16][quad * 8]);
      f16x8 b1 = *(const f16x8*)(&Vs[cur][ot * 16 + l16][32 + quad * 8]);
      Oacc[ot] = __builtin_amdgcn_mfma_f32_16x16x32_f16(pa0, b0, Oacc[ot], 0, 0, 0);
      Oacc[ot] = __builtin_amdgcn_mfma_f32_16x16x32_f16(pa1, b1, Oacc[ot], 0, 0, 0);
    }
    // row-sum of P via all-ones B (every lane gets the sum)
    Lacc = __builtin_amdgcn_mfma_f32_16x16x32_f16(pa0, ONES, Lacc, 0, 0, 0);
    Lacc = __builtin_amdgcn_mfma_f32_16x16x32_f16(pa1, ONES, Lacc, 0, 0, 0);

    __syncthreads();  // single barrier: buf[nxt] writes done, buf[cur] reads done
  }

  float* Op = Opart + (size_t)ksec * (N_TOK * 128);
#pragma unroll
  for (int ot = 0; ot < 8; ++ot)
#pragma unroll
    for (int r = 0; r < 4; ++r) {
      int row = qb + wave * 16 + quad * 4 + r;
      Op[(size_t)row * 128 + ot * 16 + l16] = Oacc[ot][r];
    }
  if (l16 == 0) {
#pragma unroll
    for (int r = 0; r < 4; ++r) {
      int row = qb + wave * 16 + quad * 4 + r;
      mpart[ksec * N_TOK + row] = m2[r];   // log2-domain (deferred) max
      lpart[ksec * N_TOK + row] = Lacc[r];
    }
  }
}

// ---------------- kernel 4: split-K combine + elu (log2 domain) --------
__global__ __launch_bounds__(256) void combine_kernel(
    const float* __restrict__ Opart, const float* __restrict__ mpart,
    const float* __restrict__ lpart, float* __restrict__ out)
{
  const int qb = blockIdx.x * 64;
  const int t = threadIdx.x;
  __shared__ float sa[NSPLIT][64], sdn[64];
  if (t < 64) {
    float m = -INFINITY;
#pragma unroll
    for (int s = 0; s < NSPLIT; ++s) m = fmaxf(m, mpart[s * N_TOK + qb + t]);
    float dn = 0.f;
#pragma unroll
    for (int s = 0; s < NSPLIT; ++s) {
      float a = exp2f(mpart[s * N_TOK + qb + t] - m);
      sa[s][t] = a;
      dn += lpart[s * N_TOK + qb + t] * a;
    }
    sdn[t] = 1.0f / dn;
  }
  __syncthreads();
  float* Og = out + (size_t)qb * 128;
#pragma unroll
  for (int i = 0; i < 8; ++i) {
    int idx = (i * 256 + t) * 4;
    int row = idx >> 7;
    f32x4 acc = (f32x4){0.f, 0.f, 0.f, 0.f};
#pragma unroll
    for (int s = 0; s < NSPLIT; ++s) {
      f32x4 o = *(const f32x4*)(Opart + (size_t)s * (N_TOK * 128) + (size_t)qb * 128 + idx);
      float a = sa[s][row];
#pragma unroll
      for (int j = 0; j < 4; ++j) acc[j] += o[j] * a;
    }
    float dn = sdn[row];
    f32x4 v;
#pragma unroll
    for (int j = 0; j < 4; ++j) {
      float x = acc[j] * dn;
      v[j] = (x > 0.f) ? x : (__expf(x) - 1.f);
    }
    *(f32x4*)(Og + idx) = v;
  }
}

// ---------------- fallback: single-pass flash (ws too small) ----------
__global__ __launch_bounds__(256) void flash1_kernel(
    const f16* __restrict__ Q, const f16* __restrict__ Kg,
    const f16* __restrict__ Vt, const int* __restrict__ adj,
    float* __restrict__ out)
{
  const int qb = blockIdx.x * 64;
  const int tid = threadIdx.x;
  const int wave = tid >> 6, lane = tid & 63, quad = lane >> 4, l16 = lane & 15;

  __shared__ __align__(16) f16 Ks[64][136];
  __shared__ __align__(16) f16 Vs[128][72];
  __shared__ __align__(16) int As[64][68];
  __shared__ __align__(16) f16 Ps[4][16][72];

  f16x8 qf[4];
#pragma unroll
  for (int ks = 0; ks < 4; ++ks)
    qf[ks] = *(const f16x8*)(Q + (size_t)(qb + wave * 16 + l16) * 128 + ks * 32 + quad * 8);
  f16x8 ONES;
#pragma unroll
  for (int j = 0; j < 8; ++j) ONES[j] = (f16)1.0f;

  f32x4 Oacc[8];
#pragma unroll
  for (int ot = 0; ot < 8; ++ot) Oacc[ot] = (f32x4){0.f, 0.f, 0.f, 0.f};
  f32x4 Lacc = (f32x4){0.f, 0.f, 0.f, 0.f};
  float m2[4];
#pragma unroll
  for (int r = 0; r < 4; ++r) m2[r] = -INFINITY;

  i32x4 pK[4], pV[4], pA[4];
#pragma unroll
  for (int i = 0; i < 4; ++i) {
    int c = i * 256 + tid;
    pK[i] = *(const i32x4*)(Kg + (size_t)(c >> 4) * 128 + (c & 15) * 8);
    pV[i] = *(const i32x4*)(Vt + (size_t)(c >> 3) * N_TOK + (c & 7) * 8);
    pA[i] = *(const i32x4*)(adj + (size_t)(qb + (c >> 4)) * N_TOK + (c & 15) * 4);
  }

  for (int it = 0; it < 256; ++it) {
    __syncthreads();
#pragma unroll
    for (int i = 0; i < 4; ++i) {
      int c = i * 256 + tid;
      *(f16x8*)(&Ks[c >> 4][(c & 15) * 8]) = __builtin_bit_cast(f16x8, pK[i]);
      *(f16x8*)(&Vs[c >> 3][(c & 7) * 8])  = __builtin_bit_cast(f16x8, pV[i]);
      *(i32x4*)(&As[c >> 4][(c & 15) * 4]) = pA[i];
    }
    __syncthreads();
    if (it + 1 < 256) {
      int kb = (it + 1) * 64;
#pragma unroll
      for (int i = 0; i < 4; ++i) {
        int c = i * 256 + tid;
        pK[i] = *(const i32x4*)(Kg + (size_t)(kb + (c >> 4)) * 128 + (c & 15) * 8);
        pV[i] = *(const i32x4*)(Vt + (size_t)(c >> 3) * N_TOK + kb + (c & 7) * 8);
        pA[i] = *(const i32x4*)(adj + (size_t)(qb + (c >> 4)) * N_TOK + kb + (c & 15) * 4);
      }
    }
    float sc[4][4];
#pragma unroll
    for (int ct = 0; ct < 4; ++ct) {
      f32x4 s = (f32x4){0.f, 0.f, 0.f, 0.f};
#pragma unroll
      for (int ks = 0; ks < 4; ++ks) {
        f16x8 b = *(const f16x8*)(&Ks[ct * 16 + l16][ks * 32 + quad * 8]);
        s = __builtin_amdgcn_mfma_f32_16x16x32_f16(qf[ks], b, s, 0, 0, 0);
      }
#pragma unroll
      for (int r = 0; r < 4; ++r) {
        float v = s[r];
        v = fmaxf(v, ALPHA_LRELU * v);
        sc[ct][r] = (As[wave * 16 + quad * 4 + r][ct * 16 + l16] > 0) ? v : NEGV;
      }
    }
    float mx[4];
#pragma unroll
    for (int r = 0; r < 4; ++r) {
      float m = fmaxf(fmaxf(sc[0][r], sc[1][r]), fmaxf(sc[2][r], sc[3][r]));
#pragma unroll
      for (int off = 8; off >= 1; off >>= 1)
        m = fmaxf(m, __shfl_xor(m, off, 16));
      mx[r] = m;
    }
    bool up = (mx[0] > m2[0] + DEFER_THR) | (mx[1] > m2[1] + DEFER_THR) |
              (mx[2] > m2[2] + DEFER_THR) | (mx[3] > m2[3] + DEFER_THR);
    if (__ballot(up)) {
      float al[4];
#pragma unroll
      for (int r = 0; r < 4; ++r) {
        float mn = fmaxf(m2[r], mx[r]);
        al[r] = exp2f(m2[r] - mn);
        m2[r] = mn;
      }
#pragma unroll
      for (int ot = 0; ot < 8; ++ot)
#pragma unroll
        for (int r = 0; r < 4; ++r) Oacc[ot][r] *= al[r];
#pragma unroll
      for (int r = 0; r < 4; ++r) Lacc[r] *= al[r];
    }
#pragma unroll
    for (int ct = 0; ct < 4; ++ct)
#pragma unroll
      for (int r = 0; r < 4; ++r)
        Ps[wave][quad * 4 + r][ct * 16 + l16] = (f16)exp2f(sc[ct][r] - m2[r]);

    asm volatile("s_waitcnt lgkmcnt(0)" ::: "memory");
    f16x8 pa0 = *(const f16x8*)(&Ps[wave][l16][quad * 8]);
    f16x8 pa1 = *(const f16x8*)(&Ps[wave][l16][32 + quad * 8]);
#pragma unroll
    for (int ot = 0; ot < 8; ++ot) {
      f16x8 b0 = *(const f16x8*)(&Vs[ot * 16 + l16][quad * 8]);
      f16x8 b1 = *(const f16x8*)(&Vs[ot * 16 + l16][32 + quad * 8]);
      Oacc[ot] = __builtin_amdgcn_mfma_f32_16x16x32_f16(pa0, b0, Oacc[ot], 0, 0, 0);
      Oacc[ot] = __builtin_amdgcn_mfma_f32_16x16x32_f16(pa1, b1, Oacc[ot], 0, 0, 0);
    }
    Lacc = __builtin_amdgcn_mfma_f32_16x16x32_f16(pa0, ONES, Lacc, 0, 0, 0);
    Lacc = __builtin_amdgcn_mfma_f32_16x16x32_f16(pa1, ONES, Lacc, 0, 0, 0);
  }
#pragma unroll
  for (int ot = 0; ot < 8; ++ot)
#pragma unroll
    for (int r = 0; r < 4; ++r) {
      float v = Oacc[ot][r] / Lacc[r];
      v = (v > 0.f) ? v : (__expf(v) - 1.f);
      int row = qb + wave * 16 + quad * 4 + r;
      out[(size_t)row * 128 + ot * 16 + l16] = v;
    }
}

extern "C" void kernel_launch(void* const* d_in, const int* in_sizes, int n_in,
                              void* d_out, int out_size, void* d_ws, size_t ws_size,
                              hipStream_t stream)
{
  const void* h  = d_in[0];
  const int* adj = (const int*)d_in[1];
  const void* Wq = d_in[2];
  const void* Wk = d_in[3];
  const void* Wv = d_in[4];
  float* out = (float*)d_out;             // fp32 [16384][128]

  char* ws = (char*)d_ws;
  int* flag = (int*)ws;                    // @0
  f16* Wt = (f16*)(ws + 1024);             // 196608 B
  f16* Q  = (f16*)(ws + 262144);           // 4 MiB
  f16* K  = (f16*)(ws + 4456448);          // 4 MiB
  f16* Vt = (f16*)(ws + 8650752);          // 4 MiB -> 12845056
  float* Opart = (float*)(ws + 12845056);  // 3 x 16384 x 128 f32 = 24 MiB
  float* mpart = (float*)(ws + 38010880);  // 3 x 16384 f32
  float* lpart = (float*)(ws + 38207488);  // 3 x 16384 f32 -> 38404096
  const size_t NEED_BASE  = 12845056;
  const size_t NEED_SPLIT = 38404096;

  if (ws_size < NEED_BASE) {
    sentinel_kernel<<<(N_TOK * 128 + 255) / 256, 256, 0, stream>>>(out);
    return;
  }

  detect_kernel<<<1, 64, 0, stream>>>((const u16*)h, flag);
  wt_kernel<<<dim3(128, 3), 256, 0, stream>>>(flag, Wq, Wk, Wv, Wt);
  qkv_kernel<<<dim3(256, 3), 256, 0, stream>>>(flag, h, Wt, Q, K, Vt);

  if (ws_size >= NEED_SPLIT) {
    // split-K x3: 768 blocks, 2 resident/CU (reg law), fine-grained backfill
    flash_kernel<<<dim3(256, NSPLIT), 256, 0, stream>>>(Q, K, Vt, adj,
                                                        Opart, mpart, lpart);
    combine_kernel<<<dim3(256), 256, 0, stream>>>(Opart, mpart, lpart, out);
  } else {
    flash1_kernel<<<dim3(256), 256, 0, stream>>>(Q, K, Vt, adj, out);
  }
}

// Round 8
// 1531.051 us; speedup vs baseline: 1.2252x; 1.0042x over previous
//
#include <hip/hip_runtime.h>

#define N_TOK 16384
#define ALPHA_LRELU 0.2f
#define NEGV -9e15f
#define NSPLIT 4
#define LOG2E 1.44269504f
#define DEFER_THR 8.0f

typedef _Float16 f16;
typedef __attribute__((ext_vector_type(4))) _Float16 f16x4;
typedef __attribute__((ext_vector_type(8))) _Float16 f16x8;
typedef __attribute__((ext_vector_type(4))) float f32x4;
typedef __attribute__((ext_vector_type(4))) int i32x4;
typedef unsigned short u16;

__device__ __forceinline__ float bf2f(u16 b) {
  unsigned u = ((unsigned)b) << 16;
  return __builtin_bit_cast(float, u);
}
__device__ __forceinline__ f16x8 cvt8(i32x4 v) {
  f16x8 r;
#pragma unroll
  for (int i = 0; i < 4; ++i) {
    unsigned u = __builtin_bit_cast(unsigned, v[i]);
    r[2 * i]     = (f16)__builtin_bit_cast(float, (u & 0xffffu) << 16);
    r[2 * i + 1] = (f16)__builtin_bit_cast(float, u & 0xffff0000u);
  }
  return r;
}

// ---------------- kernel 0: input dtype detection (EVEN u16 parity) ----
__global__ __launch_bounds__(64) void detect_kernel(const u16* __restrict__ h16,
                                                    int* __restrict__ flag)
{
  int lane = threadIdx.x;
  unsigned u = h16[lane * 2];
  unsigned e = (u >> 7) & 0xFFu;
  int sane = (e >= 0x60u && e <= 0x8Eu) ? 1 : 0;
#pragma unroll
  for (int off = 32; off >= 1; off >>= 1) sane += __shfl_xor(sane, off);
  if (lane == 0) *flag = (sane >= 32) ? 1 : 0;  // 1 = bf16 inputs, 0 = fp32
}

// ---------------- kernel 0.5: ws-too-small sentinel ----------------
__global__ __launch_bounds__(256) void sentinel_kernel(float* __restrict__ out) {
  int i = blockIdx.x * 256 + threadIdx.x;
  if (i < N_TOK * 128) out[i] = 100.0f;
}

// ---------------- kernel 1: W transpose -> fp16 ----------------
// W_query additionally scaled by log2(e): scores arrive in log2 domain
// (leakyrelu commutes with positive scaling), so softmax uses exp2 directly.
__global__ __launch_bounds__(256) void wt_kernel(
    const int* __restrict__ flag,
    const void* __restrict__ Wq, const void* __restrict__ Wk,
    const void* __restrict__ Wv, f16* __restrict__ Wt)
{
  const int isbf = *flag;
  int w = blockIdx.y;
  const void* W = (w == 0) ? Wq : (w == 1) ? Wk : Wv;
  int idx = blockIdx.x * 256 + threadIdx.x;
  int k = idx >> 7, n = idx & 127;
  float v = isbf ? bf2f(((const u16*)W)[idx]) : ((const float*)W)[idx];
  if (w == 0) v *= LOG2E;
  Wt[w * 32768 + n * 256 + k] = (f16)v;
}

// ---------------- kernel 2: fused QKV GEMM ----------------
__global__ __launch_bounds__(256) void qkv_kernel(
    const int* __restrict__ flag, const void* __restrict__ hvp,
    const f16* __restrict__ Wt,
    f16* __restrict__ Qo, f16* __restrict__ Ko, f16* __restrict__ Vt)
{
  const int isbf = *flag;
  const int mb = blockIdx.x * 64;
  const int gy = blockIdx.y;
  const int tid = threadIdx.x;
  const int wave = tid >> 6, lane = tid & 63, quad = lane >> 4, l16 = lane & 15;

  __shared__ __align__(16) f16 hs[64][256 + 8];

  if (isbf) {
    const u16* h = (const u16*)hvp;
#pragma unroll
    for (int i = 0; i < 8; ++i) {
      int c = i * 256 + tid;
      int r = c >> 5, o = c & 31;
      i32x4 v = *(const i32x4*)(h + (size_t)(mb + r) * 256 + o * 8);
      *(f16x8*)(&hs[r][o * 8]) = cvt8(v);
    }
  } else {
    const float* h = (const float*)hvp;
#pragma unroll
    for (int i = 0; i < 8; ++i) {
      int c = i * 256 + tid;
      int r = c >> 5, o = c & 31;
      const float* p = h + (size_t)(mb + r) * 256 + o * 8;
      f32x4 v0 = *(const f32x4*)p, v1 = *(const f32x4*)(p + 4);
      f16x8 q;
#pragma unroll
      for (int j = 0; j < 4; ++j) { q[j] = (f16)v0[j]; q[4 + j] = (f16)v1[j]; }
      *(f16x8*)(&hs[r][o * 8]) = q;
    }
  }
  __syncthreads();

  const f16* Wg = Wt + gy * 32768;

  if (gy < 2) {
    f16x8 a[8];
#pragma unroll
    for (int ks = 0; ks < 8; ++ks)
      a[ks] = *(const f16x8*)(&hs[wave * 16 + l16][ks * 32 + quad * 8]);
    f32x4 acc[8];
#pragma unroll
    for (int ct = 0; ct < 8; ++ct) acc[ct] = (f32x4){0.f, 0.f, 0.f, 0.f};
#pragma unroll
    for (int ks = 0; ks < 8; ++ks)
#pragma unroll
      for (int ct = 0; ct < 8; ++ct) {
        f16x8 b = *(const f16x8*)(Wg + (ct * 16 + l16) * 256 + ks * 32 + quad * 8);
        acc[ct] = __builtin_amdgcn_mfma_f32_16x16x32_f16(a[ks], b, acc[ct], 0, 0, 0);
      }
    f16* O = (gy == 0) ? Qo : Ko;
#pragma unroll
    for (int ct = 0; ct < 8; ++ct)
#pragma unroll
      for (int r = 0; r < 4; ++r)
        O[(size_t)(mb + wave * 16 + quad * 4 + r) * 128 + ct * 16 + l16] = (f16)acc[ct][r];
  } else {
    f32x4 acc[2][4];
#pragma unroll
    for (int ft = 0; ft < 2; ++ft)
#pragma unroll
      for (int bt = 0; bt < 4; ++bt) acc[ft][bt] = (f32x4){0.f, 0.f, 0.f, 0.f};
#pragma unroll
    for (int ks = 0; ks < 8; ++ks) {
      f16x8 a2[2], b2[4];
#pragma unroll
      for (int ft = 0; ft < 2; ++ft)
        a2[ft] = *(const f16x8*)(Wg + ((wave * 2 + ft) * 16 + l16) * 256 + ks * 32 + quad * 8);
#pragma unroll
      for (int bt = 0; bt < 4; ++bt)
        b2[bt] = *(const f16x8*)(&hs[bt * 16 + l16][ks * 32 + quad * 8]);
#pragma unroll
      for (int ft = 0; ft < 2; ++ft)
#pragma unroll
        for (int bt = 0; bt < 4; ++bt)
          acc[ft][bt] = __builtin_amdgcn_mfma_f32_16x16x32_f16(a2[ft], b2[bt], acc[ft][bt], 0, 0, 0);
    }
#pragma unroll
    for (int ft = 0; ft < 2; ++ft)
#pragma unroll
      for (int bt = 0; bt < 4; ++bt)
#pragma unroll
        for (int r = 0; r < 4; ++r)
          Vt[(size_t)((wave * 2 + ft) * 16 + quad * 4 + r) * N_TOK + mb + bt * 16 + l16] =
              (f16)acc[ft][bt][r];
  }
}

// ---------------- kernel 3: flash attention, QBLK=128, swapped QK^T ----
// Each wave owns 32 Q-rows (two 16-row subtiles A/B). One K-fragment read
// feeds TWO QK MFMAs (A and B) — LDS reads per FLOP halved on the QK side.
// QK computed SWAPPED: s = mfma(Kfrag, qf, s) -> S^T, so a lane's 16 scores
// all belong to q-row l16: row-max = 15 fmax + 2 shfl_xor; m2 is a scalar;
// P written as 4 contiguous b64 (vs 16 scattered b16). Ps[4][16][72] reused
// per subtile (wave-private, wave-ordered LDS => no extra barrier).
// REGISTER LAW: (256,2) cap. LDS 80896 B -> exactly 2 blocks/CU.
__global__ __launch_bounds__(256, 2) void flash_kernel(
    const f16* __restrict__ Q, const f16* __restrict__ Kg,
    const f16* __restrict__ Vt, const int* __restrict__ adj,
    float* __restrict__ Opart, float* __restrict__ mpart,
    float* __restrict__ lpart)
{
  const int qb = blockIdx.x * 128;
  const int ksec = blockIdx.y;
  const int iters = 256 / NSPLIT;        // 64
  const int kb0 = ksec * iters * 64;
  const int tid = threadIdx.x;
  const int wave = tid >> 6, lane = tid & 63, quad = lane >> 4, l16 = lane & 15;

  __shared__ __align__(16) f16 Ks[2][64][136];
  __shared__ __align__(16) f16 Vs[2][128][72];
  __shared__ __align__(16) f16 Ps[4][16][72];

  // Q fragments for both subtiles (B-operand layout == A layout; same regs)
  f16x8 qfA[4], qfB[4];
  const f16* qp = Q + (size_t)(qb + wave * 32 + l16) * 128;
#pragma unroll
  for (int ks = 0; ks < 4; ++ks) {
    qfA[ks] = *(const f16x8*)(qp + ks * 32 + quad * 8);
    qfB[ks] = *(const f16x8*)(qp + 16 * 128 + ks * 32 + quad * 8);
  }

  f16x8 ONES;
#pragma unroll
  for (int j = 0; j < 8; ++j) ONES[j] = (f16)1.0f;

  // adjacency row pointers: lane's q-rows are (qb+wave*32+l16) and +16
  const int* aprA = adj + (size_t)(qb + wave * 32 + l16) * N_TOK;
  const int* aprB = aprA + (size_t)16 * N_TOK;

  f32x4 OA[8], OB[8];
#pragma unroll
  for (int ot = 0; ot < 8; ++ot) {
    OA[ot] = (f32x4){0.f, 0.f, 0.f, 0.f};
    OB[ot] = (f32x4){0.f, 0.f, 0.f, 0.f};
  }
  f32x4 LA = (f32x4){0.f, 0.f, 0.f, 0.f};
  f32x4 LB = (f32x4){0.f, 0.f, 0.f, 0.f};
  float mA = -INFINITY, mB = -INFINITY;

  i32x4 pK[4], pV[4];
  unsigned amA, amB;  // mask bits: bit (ct*4+r) = adj[q][kv=ct*16+quad*4+r]>0

  // -------- prologue: tile0 loads + masks, stage buf0, prefetch tile1 ----
#pragma unroll
  for (int i = 0; i < 4; ++i) {
    int c = i * 256 + tid;
    pK[i] = *(const i32x4*)(Kg + (size_t)(kb0 + (c >> 4)) * 128 + (c & 15) * 8);
    pV[i] = *(const i32x4*)(Vt + (size_t)(c >> 3) * N_TOK + kb0 + (c & 7) * 8);
  }
  {
    unsigned a0 = 0, b0 = 0;
#pragma unroll
    for (int ct = 0; ct < 4; ++ct)
#pragma unroll
      for (int r = 0; r < 4; ++r) {
        int col = kb0 + ct * 16 + quad * 4 + r;
        a0 |= (unsigned)(aprA[col] > 0) << (ct * 4 + r);
        b0 |= (unsigned)(aprB[col] > 0) << (ct * 4 + r);
      }
    amA = a0; amB = b0;
  }
#pragma unroll
  for (int i = 0; i < 4; ++i) {
    int c = i * 256 + tid;
    *(f16x8*)(&Ks[0][c >> 4][(c & 15) * 8]) = __builtin_bit_cast(f16x8, pK[i]);
    *(f16x8*)(&Vs[0][c >> 3][(c & 7) * 8])  = __builtin_bit_cast(f16x8, pV[i]);
  }
  if (iters > 1) {
    int kb = kb0 + 64;
#pragma unroll
    for (int i = 0; i < 4; ++i) {
      int c = i * 256 + tid;
      pK[i] = *(const i32x4*)(Kg + (size_t)(kb + (c >> 4)) * 128 + (c & 15) * 8);
      pV[i] = *(const i32x4*)(Vt + (size_t)(c >> 3) * N_TOK + kb + (c & 7) * 8);
    }
  }
  __syncthreads();

  for (int it = 0; it < iters; ++it) {
    const int cur = it & 1;
    const int nxt = cur ^ 1;
    const int kbn = kb0 + (it + 1) * 64;

    // 1. write tile it+1 into other buffer (overlaps compute of buf cur)
    if (it + 1 < iters) {
#pragma unroll
      for (int i = 0; i < 4; ++i) {
        int c = i * 256 + tid;
        *(f16x8*)(&Ks[nxt][c >> 4][(c & 15) * 8]) = __builtin_bit_cast(f16x8, pK[i]);
        *(f16x8*)(&Vs[nxt][c >> 3][(c & 7) * 8])  = __builtin_bit_cast(f16x8, pV[i]);
      }
    }
    // 2. issue K/V loads for tile it+2
    if (it + 2 < iters) {
      int kb = kb0 + (it + 2) * 64;
#pragma unroll
      for (int i = 0; i < 4; ++i) {
        int c = i * 256 + tid;
        pK[i] = *(const i32x4*)(Kg + (size_t)(kb + (c >> 4)) * 128 + (c & 15) * 8);
        pV[i] = *(const i32x4*)(Vt + (size_t)(c >> 3) * N_TOK + kb + (c & 7) * 8);
      }
    }

    // 3. QK^T swapped, shared K-fragment: sX[ct][r] = S[q=l16][kv=ct*16+quad*4+r]
    f32x4 sA[4], sB[4];
#pragma unroll
    for (int ct = 0; ct < 4; ++ct) {
      sA[ct] = (f32x4){0.f, 0.f, 0.f, 0.f};
      sB[ct] = (f32x4){0.f, 0.f, 0.f, 0.f};
    }
#pragma unroll
    for (int ct = 0; ct < 4; ++ct)
#pragma unroll
      for (int ks = 0; ks < 4; ++ks) {
        f16x8 a = *(const f16x8*)(&Ks[cur][ct * 16 + l16][ks * 32 + quad * 8]);
        sA[ct] = __builtin_amdgcn_mfma_f32_16x16x32_f16(a, qfA[ks], sA[ct], 0, 0, 0);
        sB[ct] = __builtin_amdgcn_mfma_f32_16x16x32_f16(a, qfB[ks], sB[ct], 0, 0, 0);
      }

    // 4. leakyrelu + adjacency mask (register bits)
    float scA[4][4], scB[4][4];
#pragma unroll
    for (int ct = 0; ct < 4; ++ct)
#pragma unroll
      for (int r = 0; r < 4; ++r) {
        float vA = sA[ct][r];
        vA = fmaxf(vA, ALPHA_LRELU * vA);
        scA[ct][r] = ((amA >> (ct * 4 + r)) & 1u) ? vA : NEGV;
        float vB = sB[ct][r];
        vB = fmaxf(vB, ALPHA_LRELU * vB);
        scB[ct][r] = ((amB >> (ct * 4 + r)) & 1u) ? vB : NEGV;
      }

    // 5. issue next tile's A-mask loads early (latency hidden under compute)
    int tmA[16], tmB[16];
    if (it + 1 < iters) {
#pragma unroll
      for (int ct = 0; ct < 4; ++ct)
#pragma unroll
        for (int r = 0; r < 4; ++r)
          tmA[ct * 4 + r] = aprA[kbn + ct * 16 + quad * 4 + r];
    }

    // 6. row max: 15 local fmax + 2 shfl_xor (full 64-kv row for q=l16)
    float mxA = scA[0][0], mxB = scB[0][0];
#pragma unroll
    for (int ct = 0; ct < 4; ++ct)
#pragma unroll
      for (int r = 0; r < 4; ++r) {
        mxA = fmaxf(mxA, scA[ct][r]);
        mxB = fmaxf(mxB, scB[ct][r]);
      }
    mxA = fmaxf(mxA, __shfl_xor(mxA, 16));
    mxA = fmaxf(mxA, __shfl_xor(mxA, 32));
    mxB = fmaxf(mxB, __shfl_xor(mxB, 16));
    mxB = fmaxf(mxB, __shfl_xor(mxB, 32));

    // defer-max: rescale only when growth > THR. alpha lives at q=l16 lanes;
    // Oacc rows are q=quad*4+r -> redistribute via shfl (rare path).
    bool up = (mxA > mA + DEFER_THR) | (mxB > mB + DEFER_THR);
    if (__ballot(up)) {
      float mnA = fmaxf(mA, mxA), alA = exp2f(mA - mnA); mA = mnA;
      float mnB = fmaxf(mB, mxB), alB = exp2f(mB - mnB); mB = mnB;
      float aOA[4], aOB[4];
#pragma unroll
      for (int r = 0; r < 4; ++r) {
        aOA[r] = __shfl(alA, quad * 4 + r);
        aOB[r] = __shfl(alB, quad * 4 + r);
      }
#pragma unroll
      for (int ot = 0; ot < 8; ++ot)
#pragma unroll
        for (int r = 0; r < 4; ++r) {
          OA[ot][r] *= aOA[r];
          OB[ot][r] *= aOB[r];
        }
#pragma unroll
      for (int r = 0; r < 4; ++r) { LA[r] *= aOA[r]; LB[r] *= aOB[r]; }
    }

    // 7. subtile A: P = exp2(sc - mA) -> Ps (4 contiguous b64), then PV
#pragma unroll
    for (int ct = 0; ct < 4; ++ct) {
      f16x4 pw;
#pragma unroll
      for (int r = 0; r < 4; ++r) pw[r] = (f16)exp2f(scA[ct][r] - mA);
      *(f16x4*)(&Ps[wave][l16][ct * 16 + quad * 4]) = pw;
    }
    asm volatile("s_waitcnt lgkmcnt(0)" ::: "memory");
    {
      f16x8 pa0 = *(const f16x8*)(&Ps[wave][l16][quad * 8]);
      f16x8 pa1 = *(const f16x8*)(&Ps[wave][l16][32 + quad * 8]);
#pragma unroll
      for (int ot = 0; ot < 8; ++ot) {
        f16x8 b0 = *(const f16x8*)(&Vs[cur][ot * 16 + l16][quad * 8]);
        f16x8 b1 = *(const f16x8*)(&Vs[cur][ot * 16 + l16][32 + quad * 8]);
        OA[ot] = __builtin_amdgcn_mfma_f32_16x16x32_f16(pa0, b0, OA[ot], 0, 0, 0);
        OA[ot] = __builtin_amdgcn_mfma_f32_16x16x32_f16(pa1, b1, OA[ot], 0, 0, 0);
      }
      LA = __builtin_amdgcn_mfma_f32_16x16x32_f16(pa0, ONES, LA, 0, 0, 0);
      LA = __builtin_amdgcn_mfma_f32_16x16x32_f16(pa1, ONES, LA, 0, 0, 0);
    }

    // 8. issue next tile's B-mask loads
    if (it + 1 < iters) {
#pragma unroll
      for (int ct = 0; ct < 4; ++ct)
#pragma unroll
        for (int r = 0; r < 4; ++r)
          tmB[ct * 4 + r] = aprB[kbn + ct * 16 + quad * 4 + r];
    }

    // 9. subtile B: overwrite Ps (wave-private, wave-ordered LDS: safe)
#pragma unroll
    for (int ct = 0; ct < 4; ++ct) {
      f16x4 pw;
#pragma unroll
      for (int r = 0; r < 4; ++r) pw[r] = (f16)exp2f(scB[ct][r] - mB);
      *(f16x4*)(&Ps[wave][l16][ct * 16 + quad * 4]) = pw;
    }
    asm volatile("s_waitcnt lgkmcnt(0)" ::: "memory");
    {
      f16x8 pa0 = *(const f16x8*)(&Ps[wave][l16][quad * 8]);
      f16x8 pa1 = *(const f16x8*)(&Ps[wave][l16][32 + quad * 8]);
#pragma unroll
      for (int ot = 0; ot < 8; ++ot) {
        f16x8 b0 = *(const f16x8*)(&Vs[cur][ot * 16 + l16][quad * 8]);
        f16x8 b1 = *(const f16x8*)(&Vs[cur][ot * 16 + l16][32 + quad * 8]);
        OB[ot] = __builtin_amdgcn_mfma_f32_16x16x32_f16(pa0, b0, OB[ot], 0, 0, 0);
        OB[ot] = __builtin_amdgcn_mfma_f32_16x16x32_f16(pa1, b1, OB[ot], 0, 0, 0);
      }
      LB = __builtin_amdgcn_mfma_f32_16x16x32_f16(pa0, ONES, LB, 0, 0, 0);
      LB = __builtin_amdgcn_mfma_f32_16x16x32_f16(pa1, ONES, LB, 0, 0, 0);
    }

    // 10. pack next masks from the prefetched values
    if (it + 1 < iters) {
      unsigned a0 = 0, b0 = 0;
#pragma unroll
      for (int j = 0; j < 16; ++j) {
        a0 |= (unsigned)(tmA[j] > 0) << j;
        b0 |= (unsigned)(tmB[j] > 0) << j;
      }
      amA = a0; amB = b0;
    }

    __syncthreads();  // buf[nxt] writes done everywhere; buf[cur] reads done
  }

  // -------- epilogue --------
  float* Op = Opart + (size_t)ksec * (N_TOK * 128);
#pragma unroll
  for (int ot = 0; ot < 8; ++ot)
#pragma unroll
    for (int r = 0; r < 4; ++r) {
      int rowA = qb + wave * 32 + quad * 4 + r;
      Op[(size_t)rowA * 128 + ot * 16 + l16] = OA[ot][r];
      Op[(size_t)(rowA + 16) * 128 + ot * 16 + l16] = OB[ot][r];
    }
  if (quad == 0) {  // m2 lives at q=l16 lanes
    mpart[ksec * N_TOK + qb + wave * 32 + l16] = mA;
    mpart[ksec * N_TOK + qb + wave * 32 + 16 + l16] = mB;
  }
  if (l16 == 0) {   // L lives at q=quad*4+r rows
#pragma unroll
    for (int r = 0; r < 4; ++r) {
      lpart[ksec * N_TOK + qb + wave * 32 + quad * 4 + r] = LA[r];
      lpart[ksec * N_TOK + qb + wave * 32 + 16 + quad * 4 + r] = LB[r];
    }
  }
}

// ---------------- kernel 4: split-K combine + elu (log2 domain) --------
__global__ __launch_bounds__(256) void combine_kernel(
    const float* __restrict__ Opart, const float* __restrict__ mpart,
    const float* __restrict__ lpart, float* __restrict__ out)
{
  const int qb = blockIdx.x * 64;
  const int t = threadIdx.x;
  __shared__ float sa[NSPLIT][64], sdn[64];
  if (t < 64) {
    float m = -INFINITY;
#pragma unroll
    for (int s = 0; s < NSPLIT; ++s) m = fmaxf(m, mpart[s * N_TOK + qb + t]);
    float dn = 0.f;
#pragma unroll
    for (int s = 0; s < NSPLIT; ++s) {
      float a = exp2f(mpart[s * N_TOK + qb + t] - m);
      sa[s][t] = a;
      dn += lpart[s * N_TOK + qb + t] * a;
    }
    sdn[t] = 1.0f / dn;
  }
  __syncthreads();
  float* Og = out + (size_t)qb * 128;
#pragma unroll
  for (int i = 0; i < 8; ++i) {
    int idx = (i * 256 + t) * 4;
    int row = idx >> 7;
    f32x4 acc = (f32x4){0.f, 0.f, 0.f, 0.f};
#pragma unroll
    for (int s = 0; s < NSPLIT; ++s) {
      f32x4 o = *(const f32x4*)(Opart + (size_t)s * (N_TOK * 128) + (size_t)qb * 128 + idx);
      float a = sa[s][row];
#pragma unroll
      for (int j = 0; j < 4; ++j) acc[j] += o[j] * a;
    }
    float dn = sdn[row];
    f32x4 v;
#pragma unroll
    for (int j = 0; j < 4; ++j) {
      float x = acc[j] * dn;
      v[j] = (x > 0.f) ? x : (__expf(x) - 1.f);
    }
    *(f32x4*)(Og + idx) = v;
  }
}

// ---------------- fallback: single-pass flash (ws too small) ----------
__global__ __launch_bounds__(256) void flash1_kernel(
    const f16* __restrict__ Q, const f16* __restrict__ Kg,
    const f16* __restrict__ Vt, const int* __restrict__ adj,
    float* __restrict__ out)
{
  const int qb = blockIdx.x * 64;
  const int tid = threadIdx.x;
  const int wave = tid >> 6, lane = tid & 63, quad = lane >> 4, l16 = lane & 15;

  __shared__ __align__(16) f16 Ks[64][136];
  __shared__ __align__(16) f16 Vs[128][72];
  __shared__ __align__(16) int As[64][68];
  __shared__ __align__(16) f16 Ps[4][16][72];

  f16x8 qf[4];
#pragma unroll
  for (int ks = 0; ks < 4; ++ks)
    qf[ks] = *(const f16x8*)(Q + (size_t)(qb + wave * 16 + l16) * 128 + ks * 32 + quad * 8);
  f16x8 ONES;
#pragma unroll
  for (int j = 0; j < 8; ++j) ONES[j] = (f16)1.0f;

  f32x4 Oacc[8];
#pragma unroll
  for (int ot = 0; ot < 8; ++ot) Oacc[ot] = (f32x4){0.f, 0.f, 0.f, 0.f};
  f32x4 Lacc = (f32x4){0.f, 0.f, 0.f, 0.f};
  float m2[4];
#pragma unroll
  for (int r = 0; r < 4; ++r) m2[r] = -INFINITY;

  i32x4 pK[4], pV[4], pA[4];
#pragma unroll
  for (int i = 0; i < 4; ++i) {
    int c = i * 256 + tid;
    pK[i] = *(const i32x4*)(Kg + (size_t)(c >> 4) * 128 + (c & 15) * 8);
    pV[i] = *(const i32x4*)(Vt + (size_t)(c >> 3) * N_TOK + (c & 7) * 8);
    pA[i] = *(const i32x4*)(adj + (size_t)(qb + (c >> 4)) * N_TOK + (c & 15) * 4);
  }

  for (int it = 0; it < 256; ++it) {
    __syncthreads();
#pragma unroll
    for (int i = 0; i < 4; ++i) {
      int c = i * 256 + tid;
      *(f16x8*)(&Ks[c >> 4][(c & 15) * 8]) = __builtin_bit_cast(f16x8, pK[i]);
      *(f16x8*)(&Vs[c >> 3][(c & 7) * 8])  = __builtin_bit_cast(f16x8, pV[i]);
      *(i32x4*)(&As[c >> 4][(c & 15) * 4]) = pA[i];
    }
    __syncthreads();
    if (it + 1 < 256) {
      int kb = (it + 1) * 64;
#pragma unroll
      for (int i = 0; i < 4; ++i) {
        int c = i * 256 + tid;
        pK[i] = *(const i32x4*)(Kg + (size_t)(kb + (c >> 4)) * 128 + (c & 15) * 8);
        pV[i] = *(const i32x4*)(Vt + (size_t)(c >> 3) * N_TOK + kb + (c & 7) * 8);
        pA[i] = *(const i32x4*)(adj + (size_t)(qb + (c >> 4)) * N_TOK + kb + (c & 15) * 4);
      }
    }
    float sc[4][4];
#pragma unroll
    for (int ct = 0; ct < 4; ++ct) {
      f32x4 s = (f32x4){0.f, 0.f, 0.f, 0.f};
#pragma unroll
      for (int ks = 0; ks < 4; ++ks) {
        f16x8 b = *(const f16x8*)(&Ks[ct * 16 + l16][ks * 32 + quad * 8]);
        s = __builtin_amdgcn_mfma_f32_16x16x32_f16(qf[ks], b, s, 0, 0, 0);
      }
#pragma unroll
      for (int r = 0; r < 4; ++r) {
        float v = s[r];
        v = fmaxf(v, ALPHA_LRELU * v);
        sc[ct][r] = (As[wave * 16 + quad * 4 + r][ct * 16 + l16] > 0) ? v : NEGV;
      }
    }
    float mx[4];
#pragma unroll
    for (int r = 0; r < 4; ++r) {
      float m = fmaxf(fmaxf(sc[0][r], sc[1][r]), fmaxf(sc[2][r], sc[3][r]));
#pragma unroll
      for (int off = 8; off >= 1; off >>= 1)
        m = fmaxf(m, __shfl_xor(m, off, 16));
      mx[r] = m;
    }
    bool up = (mx[0] > m2[0] + DEFER_THR) | (mx[1] > m2[1] + DEFER_THR) |
              (mx[2] > m2[2] + DEFER_THR) | (mx[3] > m2[3] + DEFER_THR);
    if (__ballot(up)) {
      float al[4];
#pragma unroll
      for (int r = 0; r < 4; ++r) {
        float mn = fmaxf(m2[r], mx[r]);
        al[r] = exp2f(m2[r] - mn);
        m2[r] = mn;
      }
#pragma unroll
      for (int ot = 0; ot < 8; ++ot)
#pragma unroll
        for (int r = 0; r < 4; ++r) Oacc[ot][r] *= al[r];
#pragma unroll
      for (int r = 0; r < 4; ++r) Lacc[r] *= al[r];
    }
#pragma unroll
    for (int ct = 0; ct < 4; ++ct)
#pragma unroll
      for (int r = 0; r < 4; ++r)
        Ps[wave][quad * 4 + r][ct * 16 + l16] = (f16)exp2f(sc[ct][r] - m2[r]);

    asm volatile("s_waitcnt lgkmcnt(0)" ::: "memory");
    f16x8 pa0 = *(const f16x8*)(&Ps[wave][l16][quad * 8]);
    f16x8 pa1 = *(const f16x8*)(&Ps[wave][l16][32 + quad * 8]);
#pragma unroll
    for (int ot = 0; ot < 8; ++ot) {
      f16x8 b0 = *(const f16x8*)(&Vs[ot * 16 + l16][quad * 8]);
      f16x8 b1 = *(const f16x8*)(&Vs[ot * 16 + l16][32 + quad * 8]);
      Oacc[ot] = __builtin_amdgcn_mfma_f32_16x16x32_f16(pa0, b0, Oacc[ot], 0, 0, 0);
      Oacc[ot] = __builtin_amdgcn_mfma_f32_16x16x32_f16(pa1, b1, Oacc[ot], 0, 0, 0);
    }
    Lacc = __builtin_amdgcn_mfma_f32_16x16x32_f16(pa0, ONES, Lacc, 0, 0, 0);
    Lacc = __builtin_amdgcn_mfma_f32_16x16x32_f16(pa1, ONES, Lacc, 0, 0, 0);
  }
#pragma unroll
  for (int ot = 0; ot < 8; ++ot)
#pragma unroll
    for (int r = 0; r < 4; ++r) {
      float v = Oacc[ot][r] / Lacc[r];
      v = (v > 0.f) ? v : (__expf(v) - 1.f);
      int row = qb + wave * 16 + quad * 4 + r;
      out[(size_t)row * 128 + ot * 16 + l16] = v;
    }
}

extern "C" void kernel_launch(void* const* d_in, const int* in_sizes, int n_in,
                              void* d_out, int out_size, void* d_ws, size_t ws_size,
                              hipStream_t stream)
{
  const void* h  = d_in[0];
  const int* adj = (const int*)d_in[1];
  const void* Wq = d_in[2];
  const void* Wk = d_in[3];
  const void* Wv = d_in[4];
  float* out = (float*)d_out;             // fp32 [16384][128]

  char* ws = (char*)d_ws;
  int* flag = (int*)ws;                    // @0
  f16* Wt = (f16*)(ws + 1024);             // 196608 B
  f16* Q  = (f16*)(ws + 262144);           // 4 MiB
  f16* K  = (f16*)(ws + 4456448);          // 4 MiB
  f16* Vt = (f16*)(ws + 8650752);          // 4 MiB -> 12845056
  float* Opart = (float*)(ws + 12845056);  // 4 x 16384 x 128 f32 = 32 MiB
  float* mpart = (float*)(ws + 46399488);  // 4 x 16384 f32 = 256 KiB
  float* lpart = (float*)(ws + 46661632);  // 4 x 16384 f32 -> 46923776
  const size_t NEED_BASE  = 12845056;
  const size_t NEED_SPLIT = 46923776;

  if (ws_size < NEED_BASE) {
    sentinel_kernel<<<(N_TOK * 128 + 255) / 256, 256, 0, stream>>>(out);
    return;
  }

  detect_kernel<<<1, 64, 0, stream>>>((const u16*)h, flag);
  wt_kernel<<<dim3(128, 3), 256, 0, stream>>>(flag, Wq, Wk, Wv, Wt);
  qkv_kernel<<<dim3(256, 3), 256, 0, stream>>>(flag, h, Wt, Q, K, Vt);

  if (ws_size >= NEED_SPLIT) {
    // QBLK=128 x split-K x4: 512 blocks = 2 resident/CU (LDS 80896 B, (256,2))
    flash_kernel<<<dim3(128, NSPLIT), 256, 0, stream>>>(Q, K, Vt, adj,
                                                        Opart, mpart, lpart);
    combine_kernel<<<dim3(256), 256, 0, stream>>>(Opart, mpart, lpart, out);
  } else {
    flash1_kernel<<<dim3(256), 256, 0, stream>>>(Q, K, Vt, adj, out);
  }
}

// Round 9
// 1489.601 us; speedup vs baseline: 1.2593x; 1.0278x over previous
//
#include <hip/hip_runtime.h>

#define N_TOK 16384
#define ALPHA_LRELU 0.2f
#define NEGV -9e15f
#define NSPLIT 3
#define LOG2E 1.44269504f
#define DEFER_THR 8.0f

typedef _Float16 f16;
typedef __attribute__((ext_vector_type(8))) _Float16 f16x8;
typedef __attribute__((ext_vector_type(4))) float f32x4;
typedef __attribute__((ext_vector_type(4))) int i32x4;
typedef unsigned short u16;

__device__ __forceinline__ float bf2f(u16 b) {
  unsigned u = ((unsigned)b) << 16;
  return __builtin_bit_cast(float, u);
}
__device__ __forceinline__ f16x8 cvt8(i32x4 v) {
  f16x8 r;
#pragma unroll
  for (int i = 0; i < 4; ++i) {
    unsigned u = __builtin_bit_cast(unsigned, v[i]);
    r[2 * i]     = (f16)__builtin_bit_cast(float, (u & 0xffffu) << 16);
    r[2 * i + 1] = (f16)__builtin_bit_cast(float, u & 0xffff0000u);
  }
  return r;
}

// HBM -> LDS direct DMA, 16 B/lane. LDS dest is wave-uniform base + lane*16.
__device__ __forceinline__ void gload16(const void* g, void* l) {
  __builtin_amdgcn_global_load_lds(
      (const __attribute__((address_space(1))) unsigned*)g,
      (__attribute__((address_space(3))) unsigned*)l, 16, 0, 0);
}

// ---------------- kernel 0: input dtype detection (EVEN u16 parity) ----
__global__ __launch_bounds__(64) void detect_kernel(const u16* __restrict__ h16,
                                                    int* __restrict__ flag)
{
  int lane = threadIdx.x;
  unsigned u = h16[lane * 2];
  unsigned e = (u >> 7) & 0xFFu;
  int sane = (e >= 0x60u && e <= 0x8Eu) ? 1 : 0;
#pragma unroll
  for (int off = 32; off >= 1; off >>= 1) sane += __shfl_xor(sane, off);
  if (lane == 0) *flag = (sane >= 32) ? 1 : 0;  // 1 = bf16 inputs, 0 = fp32
}

// ---------------- kernel 0.5: ws-too-small sentinel ----------------
__global__ __launch_bounds__(256) void sentinel_kernel(float* __restrict__ out) {
  int i = blockIdx.x * 256 + threadIdx.x;
  if (i < N_TOK * 128) out[i] = 100.0f;
}

// ---------------- kernel 1: W transpose -> fp16 ----------------
// W_query additionally scaled by log2(e): scores arrive in log2 domain
// (leakyrelu commutes with positive scaling), so softmax uses exp2 directly.
__global__ __launch_bounds__(256) void wt_kernel(
    const int* __restrict__ flag,
    const void* __restrict__ Wq, const void* __restrict__ Wk,
    const void* __restrict__ Wv, f16* __restrict__ Wt)
{
  const int isbf = *flag;
  int w = blockIdx.y;
  const void* W = (w == 0) ? Wq : (w == 1) ? Wk : Wv;
  int idx = blockIdx.x * 256 + threadIdx.x;
  int k = idx >> 7, n = idx & 127;
  float v = isbf ? bf2f(((const u16*)W)[idx]) : ((const float*)W)[idx];
  if (w == 0) v *= LOG2E;
  Wt[w * 32768 + n * 256 + k] = (f16)v;
}

// ---------------- kernel 2: fused QKV GEMM ----------------
__global__ __launch_bounds__(256) void qkv_kernel(
    const int* __restrict__ flag, const void* __restrict__ hvp,
    const f16* __restrict__ Wt,
    f16* __restrict__ Qo, f16* __restrict__ Ko, f16* __restrict__ Vt)
{
  const int isbf = *flag;
  const int mb = blockIdx.x * 64;
  const int gy = blockIdx.y;
  const int tid = threadIdx.x;
  const int wave = tid >> 6, lane = tid & 63, quad = lane >> 4, l16 = lane & 15;

  __shared__ __align__(16) f16 hs[64][256 + 8];

  if (isbf) {
    const u16* h = (const u16*)hvp;
#pragma unroll
    for (int i = 0; i < 8; ++i) {
      int c = i * 256 + tid;
      int r = c >> 5, o = c & 31;
      i32x4 v = *(const i32x4*)(h + (size_t)(mb + r) * 256 + o * 8);
      *(f16x8*)(&hs[r][o * 8]) = cvt8(v);
    }
  } else {
    const float* h = (const float*)hvp;
#pragma unroll
    for (int i = 0; i < 8; ++i) {
      int c = i * 256 + tid;
      int r = c >> 5, o = c & 31;
      const float* p = h + (size_t)(mb + r) * 256 + o * 8;
      f32x4 v0 = *(const f32x4*)p, v1 = *(const f32x4*)(p + 4);
      f16x8 q;
#pragma unroll
      for (int j = 0; j < 4; ++j) { q[j] = (f16)v0[j]; q[4 + j] = (f16)v1[j]; }
      *(f16x8*)(&hs[r][o * 8]) = q;
    }
  }
  __syncthreads();

  const f16* Wg = Wt + gy * 32768;

  if (gy < 2) {
    f16x8 a[8];
#pragma unroll
    for (int ks = 0; ks < 8; ++ks)
      a[ks] = *(const f16x8*)(&hs[wave * 16 + l16][ks * 32 + quad * 8]);
    f32x4 acc[8];
#pragma unroll
    for (int ct = 0; ct < 8; ++ct) acc[ct] = (f32x4){0.f, 0.f, 0.f, 0.f};
#pragma unroll
    for (int ks = 0; ks < 8; ++ks)
#pragma unroll
      for (int ct = 0; ct < 8; ++ct) {
        f16x8 b = *(const f16x8*)(Wg + (ct * 16 + l16) * 256 + ks * 32 + quad * 8);
        acc[ct] = __builtin_amdgcn_mfma_f32_16x16x32_f16(a[ks], b, acc[ct], 0, 0, 0);
      }
    f16* O = (gy == 0) ? Qo : Ko;
#pragma unroll
    for (int ct = 0; ct < 8; ++ct)
#pragma unroll
      for (int r = 0; r < 4; ++r)
        O[(size_t)(mb + wave * 16 + quad * 4 + r) * 128 + ct * 16 + l16] = (f16)acc[ct][r];
  } else {
    f32x4 acc[2][4];
#pragma unroll
    for (int ft = 0; ft < 2; ++ft)
#pragma unroll
      for (int bt = 0; bt < 4; ++bt) acc[ft][bt] = (f32x4){0.f, 0.f, 0.f, 0.f};
#pragma unroll
    for (int ks = 0; ks < 8; ++ks) {
      f16x8 a2[2], b2[4];
#pragma unroll
      for (int ft = 0; ft < 2; ++ft)
        a2[ft] = *(const f16x8*)(Wg + ((wave * 2 + ft) * 16 + l16) * 256 + ks * 32 + quad * 8);
#pragma unroll
      for (int bt = 0; bt < 4; ++bt)
        b2[bt] = *(const f16x8*)(&hs[bt * 16 + l16][ks * 32 + quad * 8]);
#pragma unroll
      for (int ft = 0; ft < 2; ++ft)
#pragma unroll
        for (int bt = 0; bt < 4; ++bt)
          acc[ft][bt] = __builtin_amdgcn_mfma_f32_16x16x32_f16(a2[ft], b2[bt], acc[ft][bt], 0, 0, 0);
    }
#pragma unroll
    for (int ft = 0; ft < 2; ++ft)
#pragma unroll
      for (int bt = 0; bt < 4; ++bt)
#pragma unroll
        for (int r = 0; r < 4; ++r)
          Vt[(size_t)((wave * 2 + ft) * 16 + quad * 4 + r) * N_TOK + mb + bt * 16 + l16] =
              (f16)acc[ft][bt][r];
  }
}

// ---------------- kernel 3: flash attention via global_load_lds --------
// R9 STRUCTURE: K/V staged by HBM->LDS DMA (no pK/pV VGPRs, no ds_writes),
// single-buffered UNPADDED tiles with XOR-swizzle (byte ^= (row&7)<<4,
// applied on the GLOBAL source AND the LDS read — rule: both sides or
// neither), m97-style two-barrier loop. State ~120 regs -> (256,3) is now
// safe (nothing left to spill/sink) -> 3 blocks/CU, 3 waves/SIMD.
// LDS = 16384(K) + 16384(V) + 9216(Ps) = 41984 B -> 3 blocks/CU.
// Tripwires: WRITE>>26MB = spill (revert R7); Occ ~24% = LDS miscount.
__global__ __launch_bounds__(256, 3) void flash_kernel(
    const f16* __restrict__ Q, const f16* __restrict__ Kg,
    const f16* __restrict__ Vt, const int* __restrict__ adj,
    float* __restrict__ Opart, float* __restrict__ mpart,
    float* __restrict__ lpart)
{
  const int qb = blockIdx.x * 64;
  const int ksec = blockIdx.y;
  const int base = 256 / NSPLIT;                 // 85
  const int rem  = 256 % NSPLIT;                 // 1
  const int iters = base + (ksec < rem ? 1 : 0); // 86,85,85
  const int tile0 = ksec * base + (ksec < rem ? ksec : rem);
  const int kb0 = tile0 * 64;
  const int tid = threadIdx.x;
  const int wave = tid >> 6, lane = tid & 63, quad = lane >> 4, l16 = lane & 15;

  __shared__ __align__(16) f16 KsL[64 * 128];   // [row][128], 256 B rows
  __shared__ __align__(16) f16 VsL[128 * 64];   // [d][64], 128 B rows
  __shared__ __align__(16) f16 Ps[4][16][72];

  const int swl = (l16 & 7) << 4;  // read-side XOR (row&7 == l16&7 for reads)

  f16x8 qf[4];
#pragma unroll
  for (int ks = 0; ks < 4; ++ks)
    qf[ks] = *(const f16x8*)(Q + (size_t)(qb + wave * 16 + l16) * 128 + ks * 32 + quad * 8);

  f16x8 ONES;
#pragma unroll
  for (int j = 0; j < 8; ++j) ONES[j] = (f16)1.0f;

  // per-lane adjacency row pointers (rows quad*4+r, col slot l16 + ct*16)
  const int* aprow[4];
#pragma unroll
  for (int r = 0; r < 4; ++r)
    aprow[r] = adj + (size_t)(qb + wave * 16 + quad * 4 + r) * N_TOK + l16;

  f32x4 Oacc[8];
#pragma unroll
  for (int ot = 0; ot < 8; ++ot) Oacc[ot] = (f32x4){0.f, 0.f, 0.f, 0.f};
  f32x4 Lacc = (f32x4){0.f, 0.f, 0.f, 0.f};
  float m2[4];
#pragma unroll
  for (int r = 0; r < 4; ++r) m2[r] = -INFINITY;

  int am[4][4];  // current tile's masks

  // staging: linear LDS (wave-uniform base + lane*16), swizzled global src
  const char* Kc = (const char*)Kg;
  const char* Vc = (const char*)Vt;
  char* Kl = (char*)KsL;
  char* Vl = (char*)VsL;

#define STAGE_KV(KB)                                                          \
  {                                                                           \
    int kb_ = (KB);                                                           \
    _Pragma("unroll")                                                         \
    for (int i = 0; i < 4; ++i) {                                             \
      int row = i * 16 + (tid >> 4);                                          \
      int colb = ((tid & 15) * 16) ^ ((row & 7) << 4);                        \
      gload16(Kc + (size_t)(kb_ + row) * 256 + colb,                          \
              Kl + i * 4096 + wave * 1024);                                   \
    }                                                                         \
    _Pragma("unroll")                                                         \
    for (int i = 0; i < 4; ++i) {                                             \
      int d = i * 32 + (tid >> 3);                                            \
      int colb = ((tid & 7) * 16) ^ ((d & 7) << 4);                           \
      gload16(Vc + (size_t)d * (N_TOK * 2) + (size_t)kb_ * 2 + colb,          \
              Vl + i * 4096 + wave * 1024);                                   \
    }                                                                         \
  }

  // -------- prologue: DMA tile0, masks tile0 --------
  STAGE_KV(kb0);
#pragma unroll
  for (int r = 0; r < 4; ++r)
#pragma unroll
    for (int ct = 0; ct < 4; ++ct)
      am[r][ct] = aprow[r][kb0 + ct * 16];
  asm volatile("s_waitcnt vmcnt(0)" ::: "memory");
  __syncthreads();

  for (int it = 0; it < iters; ++it) {
    // 1. QK^T from swizzled K tile; leakyrelu; mask from registers
    float sc[4][4];
#pragma unroll
    for (int ct = 0; ct < 4; ++ct) {
      f32x4 s = (f32x4){0.f, 0.f, 0.f, 0.f};
#pragma unroll
      for (int ks = 0; ks < 4; ++ks) {
        f16x8 b = *(const f16x8*)((const char*)KsL + (ct * 16 + l16) * 256 +
                                  ((ks * 64 + quad * 16) ^ swl));
        s = __builtin_amdgcn_mfma_f32_16x16x32_f16(qf[ks], b, s, 0, 0, 0);
      }
#pragma unroll
      for (int r = 0; r < 4; ++r) {
        float v = s[r];
        v = fmaxf(v, ALPHA_LRELU * v);
        sc[ct][r] = (am[r][ct] > 0) ? v : NEGV;
      }
    }
    // 2. prefetch next tile's masks (AFTER use — WAR pins order)
    if (it + 1 < iters) {
      int kb = kb0 + (it + 1) * 64;
#pragma unroll
      for (int r = 0; r < 4; ++r)
#pragma unroll
        for (int ct = 0; ct < 4; ++ct)
          am[r][ct] = aprow[r][kb + ct * 16];
    }

    // 3. tile row max (16-lane butterfly within quad)
    float mx[4];
#pragma unroll
    for (int r = 0; r < 4; ++r) {
      float m = fmaxf(fmaxf(sc[0][r], sc[1][r]), fmaxf(sc[2][r], sc[3][r]));
#pragma unroll
      for (int off = 8; off >= 1; off >>= 1)
        m = fmaxf(m, __shfl_xor(m, off, 16));
      mx[r] = m;
    }
    // defer-max: rescale only when growth > THR (P <= 2^8 fits f16)
    bool up = (mx[0] > m2[0] + DEFER_THR) | (mx[1] > m2[1] + DEFER_THR) |
              (mx[2] > m2[2] + DEFER_THR) | (mx[3] > m2[3] + DEFER_THR);
    if (__ballot(up)) {
      float al[4];
#pragma unroll
      for (int r = 0; r < 4; ++r) {
        float mn = fmaxf(m2[r], mx[r]);
        al[r] = exp2f(m2[r] - mn);
        m2[r] = mn;
      }
#pragma unroll
      for (int ot = 0; ot < 8; ++ot)
#pragma unroll
        for (int r = 0; r < 4; ++r) Oacc[ot][r] *= al[r];
#pragma unroll
      for (int r = 0; r < 4; ++r) Lacc[r] *= al[r];
    }

    // 4. P = exp2(sc - m2) -> Ps (padded, unchanged layout), then PV
#pragma unroll
    for (int ct = 0; ct < 4; ++ct)
#pragma unroll
      for (int r = 0; r < 4; ++r)
        Ps[wave][quad * 4 + r][ct * 16 + l16] = (f16)exp2f(sc[ct][r] - m2[r]);

    asm volatile("s_waitcnt lgkmcnt(0)" ::: "memory");
    f16x8 pa0 = *(const f16x8*)(&Ps[wave][l16][quad * 8]);
    f16x8 pa1 = *(const f16x8*)(&Ps[wave][l16][32 + quad * 8]);
#pragma unroll
    for (int ot = 0; ot < 8; ++ot) {
      const char* vrow = (const char*)VsL + (ot * 16 + l16) * 128;
      f16x8 b0 = *(const f16x8*)(vrow + ((quad * 16) ^ swl));
      f16x8 b1 = *(const f16x8*)(vrow + ((64 + quad * 16) ^ swl));
      Oacc[ot] = __builtin_amdgcn_mfma_f32_16x16x32_f16(pa0, b0, Oacc[ot], 0, 0, 0);
      Oacc[ot] = __builtin_amdgcn_mfma_f32_16x16x32_f16(pa1, b1, Oacc[ot], 0, 0, 0);
    }
    Lacc = __builtin_amdgcn_mfma_f32_16x16x32_f16(pa0, ONES, Lacc, 0, 0, 0);
    Lacc = __builtin_amdgcn_mfma_f32_16x16x32_f16(pa1, ONES, Lacc, 0, 0, 0);

    // 5. all waves done reading tile it -> DMA tile it+1 over it
    __syncthreads();
    if (it + 1 < iters) {
      STAGE_KV(kb0 + (it + 1) * 64);
    }
    asm volatile("s_waitcnt vmcnt(0)" ::: "memory");
    __syncthreads();
  }
#undef STAGE_KV

  float* Op = Opart + (size_t)ksec * (N_TOK * 128);
#pragma unroll
  for (int ot = 0; ot < 8; ++ot)
#pragma unroll
    for (int r = 0; r < 4; ++r) {
      int row = qb + wave * 16 + quad * 4 + r;
      Op[(size_t)row * 128 + ot * 16 + l16] = Oacc[ot][r];
    }
  if (l16 == 0) {
#pragma unroll
    for (int r = 0; r < 4; ++r) {
      int row = qb + wave * 16 + quad * 4 + r;
      mpart[ksec * N_TOK + row] = m2[r];   // log2-domain (deferred) max
      lpart[ksec * N_TOK + row] = Lacc[r];
    }
  }
}

// ---------------- kernel 4: split-K combine + elu (log2 domain) --------
__global__ __launch_bounds__(256) void combine_kernel(
    const float* __restrict__ Opart, const float* __restrict__ mpart,
    const float* __restrict__ lpart, float* __restrict__ out)
{
  const int qb = blockIdx.x * 64;
  const int t = threadIdx.x;
  __shared__ float sa[NSPLIT][64], sdn[64];
  if (t < 64) {
    float m = -INFINITY;
#pragma unroll
    for (int s = 0; s < NSPLIT; ++s) m = fmaxf(m, mpart[s * N_TOK + qb + t]);
    float dn = 0.f;
#pragma unroll
    for (int s = 0; s < NSPLIT; ++s) {
      float a = exp2f(mpart[s * N_TOK + qb + t] - m);
      sa[s][t] = a;
      dn += lpart[s * N_TOK + qb + t] * a;
    }
    sdn[t] = 1.0f / dn;
  }
  __syncthreads();
  float* Og = out + (size_t)qb * 128;
#pragma unroll
  for (int i = 0; i < 8; ++i) {
    int idx = (i * 256 + t) * 4;
    int row = idx >> 7;
    f32x4 acc = (f32x4){0.f, 0.f, 0.f, 0.f};
#pragma unroll
    for (int s = 0; s < NSPLIT; ++s) {
      f32x4 o = *(const f32x4*)(Opart + (size_t)s * (N_TOK * 128) + (size_t)qb * 128 + idx);
      float a = sa[s][row];
#pragma unroll
      for (int j = 0; j < 4; ++j) acc[j] += o[j] * a;
    }
    float dn = sdn[row];
    f32x4 v;
#pragma unroll
    for (int j = 0; j < 4; ++j) {
      float x = acc[j] * dn;
      v[j] = (x > 0.f) ? x : (__expf(x) - 1.f);
    }
    *(f32x4*)(Og + idx) = v;
  }
}

// ---------------- fallback: single-pass flash (ws too small) ----------
__global__ __launch_bounds__(256) void flash1_kernel(
    const f16* __restrict__ Q, const f16* __restrict__ Kg,
    const f16* __restrict__ Vt, const int* __restrict__ adj,
    float* __restrict__ out)
{
  const int qb = blockIdx.x * 64;
  const int tid = threadIdx.x;
  const int wave = tid >> 6, lane = tid & 63, quad = lane >> 4, l16 = lane & 15;

  __shared__ __align__(16) f16 Ks[64][136];
  __shared__ __align__(16) f16 Vs[128][72];
  __shared__ __align__(16) int As[64][68];
  __shared__ __align__(16) f16 Ps[4][16][72];

  f16x8 qf[4];
#pragma unroll
  for (int ks = 0; ks < 4; ++ks)
    qf[ks] = *(const f16x8*)(Q + (size_t)(qb + wave * 16 + l16) * 128 + ks * 32 + quad * 8);
  f16x8 ONES;
#pragma unroll
  for (int j = 0; j < 8; ++j) ONES[j] = (f16)1.0f;

  f32x4 Oacc[8];
#pragma unroll
  for (int ot = 0; ot < 8; ++ot) Oacc[ot] = (f32x4){0.f, 0.f, 0.f, 0.f};
  f32x4 Lacc = (f32x4){0.f, 0.f, 0.f, 0.f};
  float m2[4];
#pragma unroll
  for (int r = 0; r < 4; ++r) m2[r] = -INFINITY;

  i32x4 pK[4], pV[4], pA[4];
#pragma unroll
  for (int i = 0; i < 4; ++i) {
    int c = i * 256 + tid;
    pK[i] = *(const i32x4*)(Kg + (size_t)(c >> 4) * 128 + (c & 15) * 8);
    pV[i] = *(const i32x4*)(Vt + (size_t)(c >> 3) * N_TOK + (c & 7) * 8);
    pA[i] = *(const i32x4*)(adj + (size_t)(qb + (c >> 4)) * N_TOK + (c & 15) * 4);
  }

  for (int it = 0; it < 256; ++it) {
    __syncthreads();
#pragma unroll
    for (int i = 0; i < 4; ++i) {
      int c = i * 256 + tid;
      *(f16x8*)(&Ks[c >> 4][(c & 15) * 8]) = __builtin_bit_cast(f16x8, pK[i]);
      *(f16x8*)(&Vs[c >> 3][(c & 7) * 8])  = __builtin_bit_cast(f16x8, pV[i]);
      *(i32x4*)(&As[c >> 4][(c & 15) * 4]) = pA[i];
    }
    __syncthreads();
    if (it + 1 < 256) {
      int kb = (it + 1) * 64;
#pragma unroll
      for (int i = 0; i < 4; ++i) {
        int c = i * 256 + tid;
        pK[i] = *(const i32x4*)(Kg + (size_t)(kb + (c >> 4)) * 128 + (c & 15) * 8);
        pV[i] = *(const i32x4*)(Vt + (size_t)(c >> 3) * N_TOK + kb + (c & 7) * 8);
        pA[i] = *(const i32x4*)(adj + (size_t)(qb + (c >> 4)) * N_TOK + kb + (c & 15) * 4);
      }
    }
    float sc[4][4];
#pragma unroll
    for (int ct = 0; ct < 4; ++ct) {
      f32x4 s = (f32x4){0.f, 0.f, 0.f, 0.f};
#pragma unroll
      for (int ks = 0; ks < 4; ++ks) {
        f16x8 b = *(const f16x8*)(&Ks[ct * 16 + l16][ks * 32 + quad * 8]);
        s = __builtin_amdgcn_mfma_f32_16x16x32_f16(qf[ks], b, s, 0, 0, 0);
      }
#pragma unroll
      for (int r = 0; r < 4; ++r) {
        float v = s[r];
        v = fmaxf(v, ALPHA_LRELU * v);
        sc[ct][r] = (As[wave * 16 + quad * 4 + r][ct * 16 + l16] > 0) ? v : NEGV;
      }
    }
    float mx[4];
#pragma unroll
    for (int r = 0; r < 4; ++r) {
      float m = fmaxf(fmaxf(sc[0][r], sc[1][r]), fmaxf(sc[2][r], sc[3][r]));
#pragma unroll
      for (int off = 8; off >= 1; off >>= 1)
        m = fmaxf(m, __shfl_xor(m, off, 16));
      mx[r] = m;
    }
    bool up = (mx[0] > m2[0] + DEFER_THR) | (mx[1] > m2[1] + DEFER_THR) |
              (mx[2] > m2[2] + DEFER_THR) | (mx[3] > m2[3] + DEFER_THR);
    if (__ballot(up)) {
      float al[4];
#pragma unroll
      for (int r = 0; r < 4; ++r) {
        float mn = fmaxf(m2[r], mx[r]);
        al[r] = exp2f(m2[r] - mn);
        m2[r] = mn;
      }
#pragma unroll
      for (int ot = 0; ot < 8; ++ot)
#pragma unroll
        for (int r = 0; r < 4; ++r) Oacc[ot][r] *= al[r];
#pragma unroll
      for (int r = 0; r < 4; ++r) Lacc[r] *= al[r];
    }
#pragma unroll
    for (int ct = 0; ct < 4; ++ct)
#pragma unroll
      for (int r = 0; r < 4; ++r)
        Ps[wave][quad * 4 + r][ct * 16 + l16] = (f16)exp2f(sc[ct][r] - m2[r]);

    asm volatile("s_waitcnt lgkmcnt(0)" ::: "memory");
    f16x8 pa0 = *(const f16x8*)(&Ps[wave][l16][quad * 8]);
    f16x8 pa1 = *(const f16x8*)(&Ps[wave][l16][32 + quad * 8]);
#pragma unroll
    for (int ot = 0; ot < 8; ++ot) {
      f16x8 b0 = *(const f16x8*)(&Vs[ot * 16 + l16][quad * 8]);
      f16x8 b1 = *(const f16x8*)(&Vs[ot * 16 + l16][32 + quad * 8]);
      Oacc[ot] = __builtin_amdgcn_mfma_f32_16x16x32_f16(pa0, b0, Oacc[ot], 0, 0, 0);
      Oacc[ot] = __builtin_amdgcn_mfma_f32_16x16x32_f16(pa1, b1, Oacc[ot], 0, 0, 0);
    }
    Lacc = __builtin_amdgcn_mfma_f32_16x16x32_f16(pa0, ONES, Lacc, 0, 0, 0);
    Lacc = __builtin_amdgcn_mfma_f32_16x16x32_f16(pa1, ONES, Lacc, 0, 0, 0);
  }
#pragma unroll
  for (int ot = 0; ot < 8; ++ot)
#pragma unroll
    for (int r = 0; r < 4; ++r) {
      float v = Oacc[ot][r] / Lacc[r];
      v = (v > 0.f) ? v : (__expf(v) - 1.f);
      int row = qb + wave * 16 + quad * 4 + r;
      out[(size_t)row * 128 + ot * 16 + l16] = v;
    }
}

extern "C" void kernel_launch(void* const* d_in, const int* in_sizes, int n_in,
                              void* d_out, int out_size, void* d_ws, size_t ws_size,
                              hipStream_t stream)
{
  const void* h  = d_in[0];
  const int* adj = (const int*)d_in[1];
  const void* Wq = d_in[2];
  const void* Wk = d_in[3];
  const void* Wv = d_in[4];
  float* out = (float*)d_out;             // fp32 [16384][128]

  char* ws = (char*)d_ws;
  int* flag = (int*)ws;                    // @0
  f16* Wt = (f16*)(ws + 1024);             // 196608 B
  f16* Q  = (f16*)(ws + 262144);           // 4 MiB
  f16* K  = (f16*)(ws + 4456448);          // 4 MiB
  f16* Vt = (f16*)(ws + 8650752);          // 4 MiB -> 12845056
  float* Opart = (float*)(ws + 12845056);  // 3 x 16384 x 128 f32 = 24 MiB
  float* mpart = (float*)(ws + 38010880);  // 3 x 16384 f32
  float* lpart = (float*)(ws + 38207488);  // 3 x 16384 f32 -> 38404096
  const size_t NEED_BASE  = 12845056;
  const size_t NEED_SPLIT = 38404096;

  if (ws_size < NEED_BASE) {
    sentinel_kernel<<<(N_TOK * 128 + 255) / 256, 256, 0, stream>>>(out);
    return;
  }

  detect_kernel<<<1, 64, 0, stream>>>((const u16*)h, flag);
  wt_kernel<<<dim3(128, 3), 256, 0, stream>>>(flag, Wq, Wk, Wv, Wt);
  qkv_kernel<<<dim3(256, 3), 256, 0, stream>>>(flag, h, Wt, Q, K, Vt);

  if (ws_size >= NEED_SPLIT) {
    // split-K x3: 768 blocks = 3 resident/CU (LDS 41984 B, DMA staging,
    // (256,3) reg cap finally safe — no prefetch registers left to spill)
    flash_kernel<<<dim3(256, NSPLIT), 256, 0, stream>>>(Q, K, Vt, adj,
                                                        Opart, mpart, lpart);
    combine_kernel<<<dim3(256), 256, 0, stream>>>(Opart, mpart, lpart, out);
  } else {
    flash1_kernel<<<dim3(256), 256, 0, stream>>>(Q, K, Vt, adj, out);
  }
}

// Round 10
// 1476.200 us; speedup vs baseline: 1.2707x; 1.0091x over previous
//
#include <hip/hip_runtime.h>

#define N_TOK 16384
#define ALPHA_LRELU 0.2f
#define NEGV -9e15f
#define NSPLIT 3
#define LOG2E 1.44269504f
#define DEFER_THR 8.0f

typedef _Float16 f16;
typedef __attribute__((ext_vector_type(8))) _Float16 f16x8;
typedef __attribute__((ext_vector_type(4))) float f32x4;
typedef __attribute__((ext_vector_type(4))) int i32x4;
typedef unsigned short u16;

__device__ __forceinline__ float bf2f(u16 b) {
  unsigned u = ((unsigned)b) << 16;
  return __builtin_bit_cast(float, u);
}
__device__ __forceinline__ f16x8 cvt8(i32x4 v) {
  f16x8 r;
#pragma unroll
  for (int i = 0; i < 4; ++i) {
    unsigned u = __builtin_bit_cast(unsigned, v[i]);
    r[2 * i]     = (f16)__builtin_bit_cast(float, (u & 0xffffu) << 16);
    r[2 * i + 1] = (f16)__builtin_bit_cast(float, u & 0xffff0000u);
  }
  return r;
}

// HBM -> LDS direct DMA, 16 B/lane. LDS dest is wave-uniform base + lane*16.
__device__ __forceinline__ void gload16(const void* g, void* l) {
  __builtin_amdgcn_global_load_lds(
      (const __attribute__((address_space(1))) unsigned*)g,
      (__attribute__((address_space(3))) unsigned*)l, 16, 0, 0);
}

// ---------------- kernel 0: input dtype detection (EVEN u16 parity) ----
__global__ __launch_bounds__(64) void detect_kernel(const u16* __restrict__ h16,
                                                    int* __restrict__ flag)
{
  int lane = threadIdx.x;
  unsigned u = h16[lane * 2];
  unsigned e = (u >> 7) & 0xFFu;
  int sane = (e >= 0x60u && e <= 0x8Eu) ? 1 : 0;
#pragma unroll
  for (int off = 32; off >= 1; off >>= 1) sane += __shfl_xor(sane, off);
  if (lane == 0) *flag = (sane >= 32) ? 1 : 0;  // 1 = bf16 inputs, 0 = fp32
}

// ---------------- kernel 0.5: ws-too-small sentinel ----------------
__global__ __launch_bounds__(256) void sentinel_kernel(float* __restrict__ out) {
  int i = blockIdx.x * 256 + threadIdx.x;
  if (i < N_TOK * 128) out[i] = 100.0f;
}

// ---------------- kernel 1: W transpose -> fp16 ----------------
// W_query additionally scaled by log2(e): scores arrive in log2 domain
// (leakyrelu commutes with positive scaling), so softmax uses exp2 directly.
__global__ __launch_bounds__(256) void wt_kernel(
    const int* __restrict__ flag,
    const void* __restrict__ Wq, const void* __restrict__ Wk,
    const void* __restrict__ Wv, f16* __restrict__ Wt)
{
  const int isbf = *flag;
  int w = blockIdx.y;
  const void* W = (w == 0) ? Wq : (w == 1) ? Wk : Wv;
  int idx = blockIdx.x * 256 + threadIdx.x;
  int k = idx >> 7, n = idx & 127;
  float v = isbf ? bf2f(((const u16*)W)[idx]) : ((const float*)W)[idx];
  if (w == 0) v *= LOG2E;
  Wt[w * 32768 + n * 256 + k] = (f16)v;
}

// ---------------- kernel 2: fused QKV GEMM ----------------
__global__ __launch_bounds__(256) void qkv_kernel(
    const int* __restrict__ flag, const void* __restrict__ hvp,
    const f16* __restrict__ Wt,
    f16* __restrict__ Qo, f16* __restrict__ Ko, f16* __restrict__ Vt)
{
  const int isbf = *flag;
  const int mb = blockIdx.x * 64;
  const int gy = blockIdx.y;
  const int tid = threadIdx.x;
  const int wave = tid >> 6, lane = tid & 63, quad = lane >> 4, l16 = lane & 15;

  __shared__ __align__(16) f16 hs[64][256 + 8];

  if (isbf) {
    const u16* h = (const u16*)hvp;
#pragma unroll
    for (int i = 0; i < 8; ++i) {
      int c = i * 256 + tid;
      int r = c >> 5, o = c & 31;
      i32x4 v = *(const i32x4*)(h + (size_t)(mb + r) * 256 + o * 8);
      *(f16x8*)(&hs[r][o * 8]) = cvt8(v);
    }
  } else {
    const float* h = (const float*)hvp;
#pragma unroll
    for (int i = 0; i < 8; ++i) {
      int c = i * 256 + tid;
      int r = c >> 5, o = c & 31;
      const float* p = h + (size_t)(mb + r) * 256 + o * 8;
      f32x4 v0 = *(const f32x4*)p, v1 = *(const f32x4*)(p + 4);
      f16x8 q;
#pragma unroll
      for (int j = 0; j < 4; ++j) { q[j] = (f16)v0[j]; q[4 + j] = (f16)v1[j]; }
      *(f16x8*)(&hs[r][o * 8]) = q;
    }
  }
  __syncthreads();

  const f16* Wg = Wt + gy * 32768;

  if (gy < 2) {
    f16x8 a[8];
#pragma unroll
    for (int ks = 0; ks < 8; ++ks)
      a[ks] = *(const f16x8*)(&hs[wave * 16 + l16][ks * 32 + quad * 8]);
    f32x4 acc[8];
#pragma unroll
    for (int ct = 0; ct < 8; ++ct) acc[ct] = (f32x4){0.f, 0.f, 0.f, 0.f};
#pragma unroll
    for (int ks = 0; ks < 8; ++ks)
#pragma unroll
      for (int ct = 0; ct < 8; ++ct) {
        f16x8 b = *(const f16x8*)(Wg + (ct * 16 + l16) * 256 + ks * 32 + quad * 8);
        acc[ct] = __builtin_amdgcn_mfma_f32_16x16x32_f16(a[ks], b, acc[ct], 0, 0, 0);
      }
    f16* O = (gy == 0) ? Qo : Ko;
#pragma unroll
    for (int ct = 0; ct < 8; ++ct)
#pragma unroll
      for (int r = 0; r < 4; ++r)
        O[(size_t)(mb + wave * 16 + quad * 4 + r) * 128 + ct * 16 + l16] = (f16)acc[ct][r];
  } else {
    f32x4 acc[2][4];
#pragma unroll
    for (int ft = 0; ft < 2; ++ft)
#pragma unroll
      for (int bt = 0; bt < 4; ++bt) acc[ft][bt] = (f32x4){0.f, 0.f, 0.f, 0.f};
#pragma unroll
    for (int ks = 0; ks < 8; ++ks) {
      f16x8 a2[2], b2[4];
#pragma unroll
      for (int ft = 0; ft < 2; ++ft)
        a2[ft] = *(const f16x8*)(Wg + ((wave * 2 + ft) * 16 + l16) * 256 + ks * 32 + quad * 8);
#pragma unroll
      for (int bt = 0; bt < 4; ++bt)
        b2[bt] = *(const f16x8*)(&hs[bt * 16 + l16][ks * 32 + quad * 8]);
#pragma unroll
      for (int ft = 0; ft < 2; ++ft)
#pragma unroll
        for (int bt = 0; bt < 4; ++bt)
          acc[ft][bt] = __builtin_amdgcn_mfma_f32_16x16x32_f16(a2[ft], b2[bt], acc[ft][bt], 0, 0, 0);
    }
#pragma unroll
    for (int ft = 0; ft < 2; ++ft)
#pragma unroll
      for (int bt = 0; bt < 4; ++bt)
#pragma unroll
        for (int r = 0; r < 4; ++r)
          Vt[(size_t)((wave * 2 + ft) * 16 + quad * 4 + r) * N_TOK + mb + bt * 16 + l16] =
              (f16)acc[ft][bt][r];
  }
}

// ---------------- kernel 3: flash attention, DMA + counted-vmcnt -------
// R10 STRUCTURE (T3/T4-minimum on R9's DMA base): raw s_barrier (no
// implicit drain — __syncthreads emits vmcnt(0) and exposes the DMA
// round trip) + counted waits. Per iter:
//   QK(t) -> [vmcnt(0) lgkm(0)] bar -> DMA K(t+1) + mask prefetch
//   -> Ps/PV(t) -> [lgkm(0)] bar -> DMA V(t+1) -> vmcnt(4) -> bar
// vmem issue order K(4),masks(16),V(4): vmcnt(4) retires K+masks, leaves
// V in flight across the barrier; V drains at next iter's vmcnt(0) after
// QK (~500cyc cover). K-DMA flies during the PV phase. 3 raw barriers
// replace 2 full-drain barriers; the drain stall is gone.
// LDS 41984 B, (256,3) -> 3 blocks/CU (R9-settled, no prefetch VGPRs).
__global__ __launch_bounds__(256, 3) void flash_kernel(
    const f16* __restrict__ Q, const f16* __restrict__ Kg,
    const f16* __restrict__ Vt, const int* __restrict__ adj,
    float* __restrict__ Opart, float* __restrict__ mpart,
    float* __restrict__ lpart)
{
  const int qb = blockIdx.x * 64;
  const int ksec = blockIdx.y;
  const int base = 256 / NSPLIT;                 // 85
  const int rem  = 256 % NSPLIT;                 // 1
  const int iters = base + (ksec < rem ? 1 : 0); // 86,85,85
  const int tile0 = ksec * base + (ksec < rem ? ksec : rem);
  const int kb0 = tile0 * 64;
  const int tid = threadIdx.x;
  const int wave = tid >> 6, lane = tid & 63, quad = lane >> 4, l16 = lane & 15;

  __shared__ __align__(16) f16 KsL[64 * 128];   // [row][128], 256 B rows
  __shared__ __align__(16) f16 VsL[128 * 64];   // [d][64], 128 B rows
  __shared__ __align__(16) f16 Ps[4][16][72];

  const int swl = (l16 & 7) << 4;  // read-side XOR

  f16x8 qf[4];
#pragma unroll
  for (int ks = 0; ks < 4; ++ks)
    qf[ks] = *(const f16x8*)(Q + (size_t)(qb + wave * 16 + l16) * 128 + ks * 32 + quad * 8);

  f16x8 ONES;
#pragma unroll
  for (int j = 0; j < 8; ++j) ONES[j] = (f16)1.0f;

  const int* aprow[4];
#pragma unroll
  for (int r = 0; r < 4; ++r)
    aprow[r] = adj + (size_t)(qb + wave * 16 + quad * 4 + r) * N_TOK + l16;

  f32x4 Oacc[8];
#pragma unroll
  for (int ot = 0; ot < 8; ++ot) Oacc[ot] = (f32x4){0.f, 0.f, 0.f, 0.f};
  f32x4 Lacc = (f32x4){0.f, 0.f, 0.f, 0.f};
  float m2[4];
#pragma unroll
  for (int r = 0; r < 4; ++r) m2[r] = -INFINITY;

  int am[4][4];

  const char* Kc = (const char*)Kg;
  const char* Vc = (const char*)Vt;
  char* Kl = (char*)KsL;
  char* Vl = (char*)VsL;

#define STAGE_K(KB)                                                           \
  {                                                                           \
    int kb_ = (KB);                                                           \
    _Pragma("unroll")                                                         \
    for (int i = 0; i < 4; ++i) {                                             \
      int row = i * 16 + (tid >> 4);                                          \
      int colb = ((tid & 15) * 16) ^ ((row & 7) << 4);                        \
      gload16(Kc + (size_t)(kb_ + row) * 256 + colb,                          \
              Kl + i * 4096 + wave * 1024);                                   \
    }                                                                         \
  }
#define STAGE_V(KB)                                                           \
  {                                                                           \
    int kb_ = (KB);                                                           \
    _Pragma("unroll")                                                         \
    for (int i = 0; i < 4; ++i) {                                             \
      int d = i * 32 + (tid >> 3);                                            \
      int colb = ((tid & 7) * 16) ^ ((d & 7) << 4);                           \
      gload16(Vc + (size_t)d * (N_TOK * 2) + (size_t)kb_ * 2 + colb,          \
              Vl + i * 4096 + wave * 1024);                                   \
    }                                                                         \
  }

  // -------- prologue: DMA tile0 + masks tile0, full drain --------
  STAGE_K(kb0);
  STAGE_V(kb0);
#pragma unroll
  for (int r = 0; r < 4; ++r)
#pragma unroll
    for (int ct = 0; ct < 4; ++ct)
      am[r][ct] = aprow[r][kb0 + ct * 16];
  asm volatile("s_waitcnt vmcnt(0)" ::: "memory");
  __builtin_amdgcn_s_barrier();
  asm volatile("" ::: "memory");

  for (int it = 0; it < iters; ++it) {
    const int kbn = kb0 + (it + 1) * 64;

    // --- QK^T from swizzled K tile; leakyrelu; mask from registers ---
    float sc[4][4];
#pragma unroll
    for (int ct = 0; ct < 4; ++ct) {
      f32x4 s = (f32x4){0.f, 0.f, 0.f, 0.f};
#pragma unroll
      for (int ks = 0; ks < 4; ++ks) {
        f16x8 b = *(const f16x8*)((const char*)KsL + (ct * 16 + l16) * 256 +
                                  ((ks * 64 + quad * 16) ^ swl));
        s = __builtin_amdgcn_mfma_f32_16x16x32_f16(qf[ks], b, s, 0, 0, 0);
      }
#pragma unroll
      for (int r = 0; r < 4; ++r) {
        float v = s[r];
        v = fmaxf(v, ALPHA_LRELU * v);
        sc[ct][r] = (am[r][ct] > 0) ? v : NEGV;
      }
    }

    // --- row max + defer-max rescale (register-only) ---
    float mx[4];
#pragma unroll
    for (int r = 0; r < 4; ++r) {
      float m = fmaxf(fmaxf(sc[0][r], sc[1][r]), fmaxf(sc[2][r], sc[3][r]));
#pragma unroll
      for (int off = 8; off >= 1; off >>= 1)
        m = fmaxf(m, __shfl_xor(m, off, 16));
      mx[r] = m;
    }
    bool up = (mx[0] > m2[0] + DEFER_THR) | (mx[1] > m2[1] + DEFER_THR) |
              (mx[2] > m2[2] + DEFER_THR) | (mx[3] > m2[3] + DEFER_THR);
    if (__ballot(up)) {
      float al[4];
#pragma unroll
      for (int r = 0; r < 4; ++r) {
        float mn = fmaxf(m2[r], mx[r]);
        al[r] = exp2f(m2[r] - mn);
        m2[r] = mn;
      }
#pragma unroll
      for (int ot = 0; ot < 8; ++ot)
#pragma unroll
        for (int r = 0; r < 4; ++r) Oacc[ot][r] *= al[r];
#pragma unroll
      for (int r = 0; r < 4; ++r) Lacc[r] *= al[r];
    }

    // --- barrier #1: Ks reads done everywhere; V(t) DMA writes visible ---
    asm volatile("s_waitcnt vmcnt(0) lgkmcnt(0)" ::: "memory");
    __builtin_amdgcn_s_barrier();
    asm volatile("" ::: "memory");

    // --- issue K(t+1) DMA (flies during PV) + mask prefetch ---
    if (it + 1 < iters) {
      STAGE_K(kbn);
#pragma unroll
      for (int r = 0; r < 4; ++r)
#pragma unroll
        for (int ct = 0; ct < 4; ++ct)
          am[r][ct] = aprow[r][kbn + ct * 16];
    }

    // --- P -> Ps, PV from Vs(t), Lacc ---
#pragma unroll
    for (int ct = 0; ct < 4; ++ct)
#pragma unroll
      for (int r = 0; r < 4; ++r)
        Ps[wave][quad * 4 + r][ct * 16 + l16] = (f16)exp2f(sc[ct][r] - m2[r]);

    asm volatile("s_waitcnt lgkmcnt(0)" ::: "memory");
    f16x8 pa0 = *(const f16x8*)(&Ps[wave][l16][quad * 8]);
    f16x8 pa1 = *(const f16x8*)(&Ps[wave][l16][32 + quad * 8]);
#pragma unroll
    for (int ot = 0; ot < 8; ++ot) {
      const char* vrow = (const char*)VsL + (ot * 16 + l16) * 128;
      f16x8 b0 = *(const f16x8*)(vrow + ((quad * 16) ^ swl));
      f16x8 b1 = *(const f16x8*)(vrow + ((64 + quad * 16) ^ swl));
      Oacc[ot] = __builtin_amdgcn_mfma_f32_16x16x32_f16(pa0, b0, Oacc[ot], 0, 0, 0);
      Oacc[ot] = __builtin_amdgcn_mfma_f32_16x16x32_f16(pa1, b1, Oacc[ot], 0, 0, 0);
    }
    Lacc = __builtin_amdgcn_mfma_f32_16x16x32_f16(pa0, ONES, Lacc, 0, 0, 0);
    Lacc = __builtin_amdgcn_mfma_f32_16x16x32_f16(pa1, ONES, Lacc, 0, 0, 0);

    // --- barrier #2: Vs reads done everywhere ---
    asm volatile("s_waitcnt lgkmcnt(0)" ::: "memory");
    __builtin_amdgcn_s_barrier();
    asm volatile("" ::: "memory");

    // --- issue V(t+1) DMA; retire K(t+1)+masks (leave V in flight) ---
    if (it + 1 < iters) {
      STAGE_V(kbn);
      asm volatile("s_waitcnt vmcnt(4)" ::: "memory");
    }

    // --- barrier #3: K(t+1) writes visible -> next QK may read ---
    __builtin_amdgcn_s_barrier();
    asm volatile("" ::: "memory");
  }
#undef STAGE_K
#undef STAGE_V

  float* Op = Opart + (size_t)ksec * (N_TOK * 128);
#pragma unroll
  for (int ot = 0; ot < 8; ++ot)
#pragma unroll
    for (int r = 0; r < 4; ++r) {
      int row = qb + wave * 16 + quad * 4 + r;
      Op[(size_t)row * 128 + ot * 16 + l16] = Oacc[ot][r];
    }
  if (l16 == 0) {
#pragma unroll
    for (int r = 0; r < 4; ++r) {
      int row = qb + wave * 16 + quad * 4 + r;
      mpart[ksec * N_TOK + row] = m2[r];   // log2-domain (deferred) max
      lpart[ksec * N_TOK + row] = Lacc[r];
    }
  }
}

// ---------------- kernel 4: split-K combine + elu (log2 domain) --------
__global__ __launch_bounds__(256) void combine_kernel(
    const float* __restrict__ Opart, const float* __restrict__ mpart,
    const float* __restrict__ lpart, float* __restrict__ out)
{
  const int qb = blockIdx.x * 64;
  const int t = threadIdx.x;
  __shared__ float sa[NSPLIT][64], sdn[64];
  if (t < 64) {
    float m = -INFINITY;
#pragma unroll
    for (int s = 0; s < NSPLIT; ++s) m = fmaxf(m, mpart[s * N_TOK + qb + t]);
    float dn = 0.f;
#pragma unroll
    for (int s = 0; s < NSPLIT; ++s) {
      float a = exp2f(mpart[s * N_TOK + qb + t] - m);
      sa[s][t] = a;
      dn += lpart[s * N_TOK + qb + t] * a;
    }
    sdn[t] = 1.0f / dn;
  }
  __syncthreads();
  float* Og = out + (size_t)qb * 128;
#pragma unroll
  for (int i = 0; i < 8; ++i) {
    int idx = (i * 256 + t) * 4;
    int row = idx >> 7;
    f32x4 acc = (f32x4){0.f, 0.f, 0.f, 0.f};
#pragma unroll
    for (int s = 0; s < NSPLIT; ++s) {
      f32x4 o = *(const f32x4*)(Opart + (size_t)s * (N_TOK * 128) + (size_t)qb * 128 + idx);
      float a = sa[s][row];
#pragma unroll
      for (int j = 0; j < 4; ++j) acc[j] += o[j] * a;
    }
    float dn = sdn[row];
    f32x4 v;
#pragma unroll
    for (int j = 0; j < 4; ++j) {
      float x = acc[j] * dn;
      v[j] = (x > 0.f) ? x : (__expf(x) - 1.f);
    }
    *(f32x4*)(Og + idx) = v;
  }
}

// ---------------- fallback: single-pass flash (ws too small) ----------
__global__ __launch_bounds__(256) void flash1_kernel(
    const f16* __restrict__ Q, const f16* __restrict__ Kg,
    const f16* __restrict__ Vt, const int* __restrict__ adj,
    float* __restrict__ out)
{
  const int qb = blockIdx.x * 64;
  const int tid = threadIdx.x;
  const int wave = tid >> 6, lane = tid & 63, quad = lane >> 4, l16 = lane & 15;

  __shared__ __align__(16) f16 Ks[64][136];
  __shared__ __align__(16) f16 Vs[128][72];
  __shared__ __align__(16) int As[64][68];
  __shared__ __align__(16) f16 Ps[4][16][72];

  f16x8 qf[4];
#pragma unroll
  for (int ks = 0; ks < 4; ++ks)
    qf[ks] = *(const f16x8*)(Q + (size_t)(qb + wave * 16 + l16) * 128 + ks * 32 + quad * 8);
  f16x8 ONES;
#pragma unroll
  for (int j = 0; j < 8; ++j) ONES[j] = (f16)1.0f;

  f32x4 Oacc[8];
#pragma unroll
  for (int ot = 0; ot < 8; ++ot) Oacc[ot] = (f32x4){0.f, 0.f, 0.f, 0.f};
  f32x4 Lacc = (f32x4){0.f, 0.f, 0.f, 0.f};
  float m2[4];
#pragma unroll
  for (int r = 0; r < 4; ++r) m2[r] = -INFINITY;

  i32x4 pK[4], pV[4], pA[4];
#pragma unroll
  for (int i = 0; i < 4; ++i) {
    int c = i * 256 + tid;
    pK[i] = *(const i32x4*)(Kg + (size_t)(c >> 4) * 128 + (c & 15) * 8);
    pV[i] = *(const i32x4*)(Vt + (size_t)(c >> 3) * N_TOK + (c & 7) * 8);
    pA[i] = *(const i32x4*)(adj + (size_t)(qb + (c >> 4)) * N_TOK + (c & 15) * 4);
  }

  for (int it = 0; it < 256; ++it) {
    __syncthreads();
#pragma unroll
    for (int i = 0; i < 4; ++i) {
      int c = i * 256 + tid;
      *(f16x8*)(&Ks[c >> 4][(c & 15) * 8]) = __builtin_bit_cast(f16x8, pK[i]);
      *(f16x8*)(&Vs[c >> 3][(c & 7) * 8])  = __builtin_bit_cast(f16x8, pV[i]);
      *(i32x4*)(&As[c >> 4][(c & 15) * 4]) = pA[i];
    }
    __syncthreads();
    if (it + 1 < 256) {
      int kb = (it + 1) * 64;
#pragma unroll
      for (int i = 0; i < 4; ++i) {
        int c = i * 256 + tid;
        pK[i] = *(const i32x4*)(Kg + (size_t)(kb + (c >> 4)) * 128 + (c & 15) * 8);
        pV[i] = *(const i32x4*)(Vt + (size_t)(c >> 3) * N_TOK + kb + (c & 7) * 8);
        pA[i] = *(const i32x4*)(adj + (size_t)(qb + (c >> 4)) * N_TOK + kb + (c & 15) * 4);
      }
    }
    float sc[4][4];
#pragma unroll
    for (int ct = 0; ct < 4; ++ct) {
      f32x4 s = (f32x4){0.f, 0.f, 0.f, 0.f};
#pragma unroll
      for (int ks = 0; ks < 4; ++ks) {
        f16x8 b = *(const f16x8*)(&Ks[ct * 16 + l16][ks * 32 + quad * 8]);
        s = __builtin_amdgcn_mfma_f32_16x16x32_f16(qf[ks], b, s, 0, 0, 0);
      }
#pragma unroll
      for (int r = 0; r < 4; ++r) {
        float v = s[r];
        v = fmaxf(v, ALPHA_LRELU * v);
        sc[ct][r] = (As[wave * 16 + quad * 4 + r][ct * 16 + l16] > 0) ? v : NEGV;
      }
    }
    float mx[4];
#pragma unroll
    for (int r = 0; r < 4; ++r) {
      float m = fmaxf(fmaxf(sc[0][r], sc[1][r]), fmaxf(sc[2][r], sc[3][r]));
#pragma unroll
      for (int off = 8; off >= 1; off >>= 1)
        m = fmaxf(m, __shfl_xor(m, off, 16));
      mx[r] = m;
    }
    bool up = (mx[0] > m2[0] + DEFER_THR) | (mx[1] > m2[1] + DEFER_THR) |
              (mx[2] > m2[2] + DEFER_THR) | (mx[3] > m2[3] + DEFER_THR);
    if (__ballot(up)) {
      float al[4];
#pragma unroll
      for (int r = 0; r < 4; ++r) {
        float mn = fmaxf(m2[r], mx[r]);
        al[r] = exp2f(m2[r] - mn);
        m2[r] = mn;
      }
#pragma unroll
      for (int ot = 0; ot < 8; ++ot)
#pragma unroll
        for (int r = 0; r < 4; ++r) Oacc[ot][r] *= al[r];
#pragma unroll
      for (int r = 0; r < 4; ++r) Lacc[r] *= al[r];
    }
#pragma unroll
    for (int ct = 0; ct < 4; ++ct)
#pragma unroll
      for (int r = 0; r < 4; ++r)
        Ps[wave][quad * 4 + r][ct * 16 + l16] = (f16)exp2f(sc[ct][r] - m2[r]);

    asm volatile("s_waitcnt lgkmcnt(0)" ::: "memory");
    f16x8 pa0 = *(const f16x8*)(&Ps[wave][l16][quad * 8]);
    f16x8 pa1 = *(const f16x8*)(&Ps[wave][l16][32 + quad * 8]);
#pragma unroll
    for (int ot = 0; ot < 8; ++ot) {
      f16x8 b0 = *(const f16x8*)(&Vs[ot * 16 + l16][quad * 8]);
      f16x8 b1 = *(const f16x8*)(&Vs[ot * 16 + l16][32 + quad * 8]);
      Oacc[ot] = __builtin_amdgcn_mfma_f32_16x16x32_f16(pa0, b0, Oacc[ot], 0, 0, 0);
      Oacc[ot] = __builtin_amdgcn_mfma_f32_16x16x32_f16(pa1, b1, Oacc[ot], 0, 0, 0);
    }
    Lacc = __builtin_amdgcn_mfma_f32_16x16x32_f16(pa0, ONES, Lacc, 0, 0, 0);
    Lacc = __builtin_amdgcn_mfma_f32_16x16x32_f16(pa1, ONES, Lacc, 0, 0, 0);
  }
#pragma unroll
  for (int ot = 0; ot < 8; ++ot)
#pragma unroll
    for (int r = 0; r < 4; ++r) {
      float v = Oacc[ot][r] / Lacc[r];
      v = (v > 0.f) ? v : (__expf(v) - 1.f);
      int row = qb + wave * 16 + quad * 4 + r;
      out[(size_t)row * 128 + ot * 16 + l16] = v;
    }
}

extern "C" void kernel_launch(void* const* d_in, const int* in_sizes, int n_in,
                              void* d_out, int out_size, void* d_ws, size_t ws_size,
                              hipStream_t stream)
{
  const void* h  = d_in[0];
  const int* adj = (const int*)d_in[1];
  const void* Wq = d_in[2];
  const void* Wk = d_in[3];
  const void* Wv = d_in[4];
  float* out = (float*)d_out;             // fp32 [16384][128]

  char* ws = (char*)d_ws;
  int* flag = (int*)ws;                    // @0
  f16* Wt = (f16*)(ws + 1024);             // 196608 B
  f16* Q  = (f16*)(ws + 262144);           // 4 MiB
  f16* K  = (f16*)(ws + 4456448);          // 4 MiB
  f16* Vt = (f16*)(ws + 8650752);          // 4 MiB -> 12845056
  float* Opart = (float*)(ws + 12845056);  // 3 x 16384 x 128 f32 = 24 MiB
  float* mpart = (float*)(ws + 38010880);  // 3 x 16384 f32
  float* lpart = (float*)(ws + 38207488);  // 3 x 16384 f32 -> 38404096
  const size_t NEED_BASE  = 12845056;
  const size_t NEED_SPLIT = 38404096;

  if (ws_size < NEED_BASE) {
    sentinel_kernel<<<(N_TOK * 128 + 255) / 256, 256, 0, stream>>>(out);
    return;
  }

  detect_kernel<<<1, 64, 0, stream>>>((const u16*)h, flag);
  wt_kernel<<<dim3(128, 3), 256, 0, stream>>>(flag, Wq, Wk, Wv, Wt);
  qkv_kernel<<<dim3(256, 3), 256, 0, stream>>>(flag, h, Wt, Q, K, Vt);

  if (ws_size >= NEED_SPLIT) {
    // split-K x3: 768 blocks = 3 resident/CU, DMA staging, counted vmcnt
    flash_kernel<<<dim3(256, NSPLIT), 256, 0, stream>>>(Q, K, Vt, adj,
                                                        Opart, mpart, lpart);
    combine_kernel<<<dim3(256), 256, 0, stream>>>(Opart, mpart, lpart, out);
  } else {
    flash1_kernel<<<dim3(256), 256, 0, stream>>>(Q, K, Vt, adj, out);
  }
}